// Round 1
// baseline (2172.487 us; speedup 1.0000x reference)
//
#include <hip/hip_runtime.h>
#include <hip/hip_bf16.h>

#define N_NODES 100000
#define N_EDGES 500000
#define HID 128
#define NEG_SLOPE 0.2f

// ---------------- CSR build ----------------

__global__ void k_hist(const int* __restrict__ dst, int* __restrict__ cnt, int nE, int n) {
    int r = blockIdx.y;
    int e = blockIdx.x * blockDim.x + threadIdx.x;
    if (e < nE) atomicAdd(&cnt[r * n + dst[r * nE + e]], 1);
}

__global__ __launch_bounds__(1024) void k_scan(const int* __restrict__ cnt,
                                               int* __restrict__ rowptr, int n) {
    int r = blockIdx.x;
    const int* c = cnt + r * n;
    int* rp = rowptr + r * (n + 1);
    __shared__ int wsum[16];
    int tid = threadIdx.x, lane = tid & 63, wid = tid >> 6;
    if (tid == 0) rp[0] = 0;
    int carry = 0;
    for (int base = 0; base < n; base += 1024) {
        int i = base + tid;
        int v = (i < n) ? c[i] : 0;
        #pragma unroll
        for (int d = 1; d < 64; d <<= 1) {
            int t = __shfl_up(v, d);
            if (lane >= d) v += t;
        }
        if (lane == 63) wsum[wid] = v;
        __syncthreads();
        if (wid == 0) {
            int s = (lane < 16) ? wsum[lane] : 0;
            #pragma unroll
            for (int d = 1; d < 16; d <<= 1) {
                int t = __shfl_up(s, d);
                if (lane >= d) s += t;
            }
            if (lane < 16) wsum[lane] = s;
        }
        __syncthreads();
        int off = (wid > 0) ? wsum[wid - 1] : 0;
        v += off + carry;
        if (i < n) rp[i + 1] = v;
        carry += wsum[15];
        __syncthreads();
    }
}

__global__ void k_copyofs(const int* __restrict__ rowptr, int* __restrict__ wofs, int n) {
    int i = blockIdx.x * blockDim.x + threadIdx.x;
    if (i < 3 * n) {
        int r = i / n, v = i - r * n;
        wofs[i] = rowptr[r * (n + 1) + v];
    }
}

__global__ void k_scatter(const int* __restrict__ src, const int* __restrict__ dst,
                          int* __restrict__ wofs, int* __restrict__ csrc, int nE, int n) {
    int r = blockIdx.y;
    int e = blockIdx.x * blockDim.x + threadIdx.x;
    if (e < nE) {
        int d = dst[r * nE + e];
        int pos = atomicAdd(&wofs[r * n + d], 1);
        csrc[(size_t)r * nE + pos] = src[r * nE + e];
    }
}

// ---------------- GEMM: feat = h @ W  ([N,128] x [128,128]) ----------------
// block = 256 threads, tile = 64 rows x 128 cols, per-thread 4x8 register tile.
__global__ __launch_bounds__(256) void k_gemm(const float* __restrict__ A,
                                              const float* __restrict__ W,
                                              float* __restrict__ out, int nrows) {
    __shared__ float Wc[128][132];  // col-major: Wc[j][k], pad 132 to break bank stride
    __shared__ float Ht[64][132];
    int tid = threadIdx.x;
    for (int i = tid; i < 4096; i += 256) {  // 128*128/4
        int k = i >> 5, j0 = (i & 31) << 2;
        float4 w = *(const float4*)(W + k * 128 + j0);
        Wc[j0 + 0][k] = w.x; Wc[j0 + 1][k] = w.y;
        Wc[j0 + 2][k] = w.z; Wc[j0 + 3][k] = w.w;
    }
    int row0 = blockIdx.x << 6;
    for (int i = tid; i < 2048; i += 256) {  // 64*128/4
        int rr = i >> 5, k0 = (i & 31) << 2;
        int gr = row0 + rr;
        float4 v = make_float4(0.f, 0.f, 0.f, 0.f);
        if (gr < nrows) v = *(const float4*)(A + (size_t)gr * 128 + k0);
        *(float4*)&Ht[rr][k0] = v;
    }
    __syncthreads();
    int tr = tid >> 4, tc = tid & 15;  // tr: 0..15 row group of 4; tc: 0..15 col
    float acc[4][8] = {};
    #pragma unroll 4
    for (int k = 0; k < 128; k += 4) {
        float4 a0 = *(float4*)&Ht[tr * 4 + 0][k];
        float4 a1 = *(float4*)&Ht[tr * 4 + 1][k];
        float4 a2 = *(float4*)&Ht[tr * 4 + 2][k];
        float4 a3 = *(float4*)&Ht[tr * 4 + 3][k];
        #pragma unroll
        for (int n = 0; n < 8; n++) {
            float4 b = *(float4*)&Wc[tc + (n << 4)][k];
            acc[0][n] += a0.x * b.x + a0.y * b.y + a0.z * b.z + a0.w * b.w;
            acc[1][n] += a1.x * b.x + a1.y * b.y + a1.z * b.z + a1.w * b.w;
            acc[2][n] += a2.x * b.x + a2.y * b.y + a2.z * b.z + a2.w * b.w;
            acc[3][n] += a3.x * b.x + a3.y * b.y + a3.z * b.z + a3.w * b.w;
        }
    }
    #pragma unroll
    for (int m = 0; m < 4; m++) {
        int gr = row0 + tr * 4 + m;
        if (gr < nrows) {
            #pragma unroll
            for (int n = 0; n < 8; n++)
                out[(size_t)gr * 128 + tc + (n << 4)] = acc[m][n];
        }
    }
}

// ---------------- el/er: per-node attention logits ----------------
// one wave per node: elr[n] = {el_h0, el_h1, er_h0, er_h1}
__global__ __launch_bounds__(256) void k_eler(const float* __restrict__ feat,
                                              const float* __restrict__ al,
                                              const float* __restrict__ ar,
                                              float4* __restrict__ elr, int nrows) {
    int wid = threadIdx.x >> 6, lane = threadIdx.x & 63;
    int n = (blockIdx.x << 2) + wid;
    if (n >= nrows) return;
    float f0 = feat[(size_t)n * 128 + lane];
    float f1 = feat[(size_t)n * 128 + 64 + lane];
    float e0 = f0 * al[lane], e1 = f1 * al[64 + lane];
    float r0 = f0 * ar[lane], r1 = f1 * ar[64 + lane];
    #pragma unroll
    for (int off = 32; off; off >>= 1) {
        e0 += __shfl_xor(e0, off); e1 += __shfl_xor(e1, off);
        r0 += __shfl_xor(r0, off); r1 += __shfl_xor(r1, off);
    }
    if (lane == 0) elr[n] = make_float4(e0, e1, r0, r1);
}

// ---------------- per-node softmax + gather-aggregate ----------------
// one wave per dst node; lane = channel (lane, lane+64). No atomics.
__global__ __launch_bounds__(256) void k_agg(const float* __restrict__ feat,
                                             const float4* __restrict__ elr,
                                             const int* __restrict__ rowptr,
                                             const int* __restrict__ csrc,
                                             const float* __restrict__ bias,
                                             float* __restrict__ acc, int nrows, int add) {
    int wid = threadIdx.x >> 6, lane = threadIdx.x & 63;
    int v = (blockIdx.x << 2) + wid;
    if (v >= nrows) return;
    int beg = rowptr[v], end = rowptr[v + 1];
    float4 ev = elr[v];
    float m0 = -1e30f, m1 = -1e30f;
    for (int i = beg; i < end; i++) {
        int s = csrc[i];
        float4 es = elr[s];
        float e0 = es.x + ev.z; e0 = e0 >= 0.f ? e0 : NEG_SLOPE * e0;
        float e1 = es.y + ev.w; e1 = e1 >= 0.f ? e1 : NEG_SLOPE * e1;
        m0 = fmaxf(m0, e0); m1 = fmaxf(m1, e1);
    }
    float s0 = 0.f, s1 = 0.f, a0 = 0.f, a1 = 0.f;
    for (int i = beg; i < end; i++) {
        int s = csrc[i];
        float4 es = elr[s];
        float e0 = es.x + ev.z; e0 = e0 >= 0.f ? e0 : NEG_SLOPE * e0;
        float e1 = es.y + ev.w; e1 = e1 >= 0.f ? e1 : NEG_SLOPE * e1;
        float p0 = __expf(e0 - m0), p1 = __expf(e1 - m1);
        s0 += p0; s1 += p1;
        a0 += p0 * feat[(size_t)s * 128 + lane];
        a1 += p1 * feat[(size_t)s * 128 + 64 + lane];
    }
    float i0 = s0 > 0.f ? 1.0f / s0 : 0.f;
    float i1 = s1 > 0.f ? 1.0f / s1 : 0.f;
    float r0 = a0 * i0 + bias[lane];
    float r1 = a1 * i1 + bias[64 + lane];
    size_t base = (size_t)v * 128 + lane;
    if (add) { acc[base] += r0; acc[base + 64] += r1; }
    else     { acc[base]  = r0; acc[base + 64]  = r1; }
}

// ---------------- elementwise relu ----------------
__global__ void k_relu(const float4* __restrict__ in, float4* __restrict__ out, int n4) {
    for (int i = blockIdx.x * blockDim.x + threadIdx.x; i < n4; i += gridDim.x * blockDim.x) {
        float4 v = in[i];
        v.x = fmaxf(v.x, 0.f); v.y = fmaxf(v.y, 0.f);
        v.z = fmaxf(v.z, 0.f); v.w = fmaxf(v.w, 0.f);
        out[i] = v;
    }
}

// ---------------- BN stats: per-channel sum & sumsq ----------------
__global__ void k_bnstat(const float* __restrict__ h, float* __restrict__ sums, int nrows) {
    int ch = threadIdx.x & 127, half = threadIdx.x >> 7;
    float s = 0.f, s2 = 0.f;
    for (int row = blockIdx.x * 2 + half; row < nrows; row += gridDim.x * 2) {
        float x = h[(size_t)row * 128 + ch];
        s += x; s2 += x * x;
    }
    atomicAdd(&sums[ch], s);
    atomicAdd(&sums[128 + ch], s2);
}

// ---------------- BN-normalize + classifier GEMM [N,128]x[128,64] ----------------
__global__ __launch_bounds__(256) void k_clf(const float* __restrict__ h,
                                             const float* __restrict__ sums,
                                             const float* __restrict__ bn_w,
                                             const float* __restrict__ bn_b,
                                             const float* __restrict__ Wc,
                                             const float* __restrict__ cb,
                                             float* __restrict__ out, int nrows) {
    __shared__ float Wt[64][128];    // Wt[c][k], XOR-swizzled in 16B groups
    __shared__ float2 bnp[128];
    __shared__ float hrow[4][128];
    int tid = threadIdx.x;
    for (int idx = tid; idx < 2048; idx += 256) {
        int k = idx >> 4, c4 = (idx & 15) << 2;
        float4 w = *(const float4*)(Wc + k * 64 + c4);
        int kk = k >> 2, kr = k & 3;
        Wt[c4 + 0][((kk ^ ((c4 + 0) & 7)) << 2) + kr] = w.x;
        Wt[c4 + 1][((kk ^ ((c4 + 1) & 7)) << 2) + kr] = w.y;
        Wt[c4 + 2][((kk ^ ((c4 + 2) & 7)) << 2) + kr] = w.z;
        Wt[c4 + 3][((kk ^ ((c4 + 3) & 7)) << 2) + kr] = w.w;
    }
    if (tid < 128) {
        float mu = sums[tid] / (float)nrows;
        float var = sums[128 + tid] / (float)nrows - mu * mu;
        float rs = rsqrtf(var + 1e-5f);
        float sc = bn_w[tid] * rs;
        bnp[tid] = make_float2(sc, bn_b[tid] - mu * sc);
    }
    __syncthreads();
    int wid = tid >> 6, lane = tid & 63;
    float cbv = cb[lane];
    for (int row = (blockIdx.x << 2) + wid; row < nrows; row += gridDim.x << 2) {
        float x0 = h[(size_t)row * 128 + lane];
        float x1 = h[(size_t)row * 128 + 64 + lane];
        hrow[wid][lane] = x0 * bnp[lane].x + bnp[lane].y;
        hrow[wid][64 + lane] = x1 * bnp[64 + lane].x + bnp[64 + lane].y;
        float acc = cbv;
        #pragma unroll
        for (int kk = 0; kk < 32; kk++) {
            float4 hv = *(float4*)&hrow[wid][kk << 2];
            float4 wv = *(float4*)&Wt[lane][(kk ^ (lane & 7)) << 2];
            acc += hv.x * wv.x + hv.y * wv.y + hv.z * wv.z + hv.w * wv.w;
        }
        out[(size_t)row * 64 + lane] = acc;
    }
}

// ---------------- launch ----------------

extern "C" void kernel_launch(void* const* d_in, const int* in_sizes, int n_in,
                              void* d_out, int out_size, void* d_ws, size_t ws_size,
                              hipStream_t stream) {
    (void)in_sizes; (void)n_in; (void)out_size; (void)ws_size;
    const float* feat_in = (const float*)d_in[0];
    const float* Ws      = (const float*)d_in[1];
    const float* als     = (const float*)d_in[2];
    const float* ars     = (const float*)d_in[3];
    const float* bs      = (const float*)d_in[4];
    const float* bn_w    = (const float*)d_in[5];
    const float* bn_b    = (const float*)d_in[6];
    const float* clf_W   = (const float*)d_in[7];
    const float* clf_b   = (const float*)d_in[8];
    const int*   src     = (const int*)d_in[9];
    const int*   dst     = (const int*)d_in[10];
    float* out = (float*)d_out;

    const int N = N_NODES, E = N_EDGES;
    char* p = (char*)d_ws;
    auto carve = [&](size_t bytes) { char* q = p; p += (bytes + 255) & ~255ULL; return q; };
    int*    wofs   = (int*)carve((size_t)3 * N * 4);
    int*    rowptr = (int*)carve((size_t)3 * (N + 1) * 4);
    int*    csrc   = (int*)carve((size_t)3 * E * 4);
    float4* elr    = (float4*)carve((size_t)N * 16);
    float*  bnsum  = (float*)carve(256 * 4);
    float*  featb  = (float*)carve((size_t)N * 128 * 4);
    float*  accb   = (float*)carve((size_t)N * 128 * 4);
    float*  h1     = (float*)carve((size_t)N * 128 * 4);

    // CSR build (reused across both layers)
    hipMemsetAsync(wofs, 0, (size_t)3 * N * 4, stream);
    dim3 ge((E + 255) / 256, 3);
    k_hist<<<ge, 256, 0, stream>>>(dst, wofs, E, N);
    k_scan<<<3, 1024, 0, stream>>>(wofs, rowptr, N);
    k_copyofs<<<(3 * N + 255) / 256, 256, 0, stream>>>(rowptr, wofs, N);
    k_scatter<<<ge, 256, 0, stream>>>(src, dst, wofs, csrc, E, N);

    const float* hin = feat_in;
    for (int l = 0; l < 2; l++) {
        for (int r = 0; r < 3; r++) {
            int lr = l * 3 + r;
            k_gemm<<<(N + 63) / 64, 256, 0, stream>>>(hin, Ws + (size_t)lr * 128 * 128, featb, N);
            k_eler<<<(N + 3) / 4, 256, 0, stream>>>(featb, als + lr * 128, ars + lr * 128, elr, N);
            k_agg<<<(N + 3) / 4, 256, 0, stream>>>(featb, elr, rowptr + r * (N + 1),
                                                   csrc + (size_t)r * E, bs + lr * 128,
                                                   accb, N, r);
        }
        float* hout = (l == 0) ? h1 : featb;
        k_relu<<<2048, 256, 0, stream>>>((const float4*)accb, (float4*)hout, N * 32);
        hin = hout;
    }

    hipMemsetAsync(bnsum, 0, 256 * 4, stream);
    k_bnstat<<<2048, 256, 0, stream>>>(featb, bnsum, N);
    k_clf<<<1024, 256, 0, stream>>>(featb, bnsum, bn_w, bn_b, clf_W, clf_b, out, N);
}

// Round 2
// 1318.578 us; speedup vs baseline: 1.6476x; 1.6476x over previous
//
#include <hip/hip_runtime.h>
#include <hip/hip_bf16.h>

#define N_NODES 100000
#define N_EDGES 500000
#define HID 128
#define NEG_SLOPE 0.2f

typedef __attribute__((ext_vector_type(8))) short short8v;
typedef __attribute__((ext_vector_type(4))) short short4v;
typedef __attribute__((ext_vector_type(4))) float f32x4;

__device__ __forceinline__ short f2bf(float x) {
    union { float f; unsigned u; } v; v.f = x;
    unsigned r = v.u + 0x7fff + ((v.u >> 16) & 1);  // RNE
    return (short)(r >> 16);
}

// ---------------- CSR build ----------------

__global__ void k_hist(const int* __restrict__ dst, int* __restrict__ cnt, int nE, int n) {
    int r = blockIdx.y;
    int e = blockIdx.x * blockDim.x + threadIdx.x;
    if (e < nE) atomicAdd(&cnt[r * n + dst[r * nE + e]], 1);
}

__global__ __launch_bounds__(1024) void k_scan(const int* __restrict__ cnt,
                                               int* __restrict__ rowptr, int n) {
    int r = blockIdx.x;
    const int* c = cnt + r * n;
    int* rp = rowptr + r * (n + 1);
    __shared__ int wsum[16];
    int tid = threadIdx.x, lane = tid & 63, wid = tid >> 6;
    if (tid == 0) rp[0] = 0;
    int carry = 0;
    for (int base = 0; base < n; base += 1024) {
        int i = base + tid;
        int v = (i < n) ? c[i] : 0;
        #pragma unroll
        for (int d = 1; d < 64; d <<= 1) {
            int t = __shfl_up(v, d);
            if (lane >= d) v += t;
        }
        if (lane == 63) wsum[wid] = v;
        __syncthreads();
        if (wid == 0) {
            int s = (lane < 16) ? wsum[lane] : 0;
            #pragma unroll
            for (int d = 1; d < 16; d <<= 1) {
                int t = __shfl_up(s, d);
                if (lane >= d) s += t;
            }
            if (lane < 16) wsum[lane] = s;
        }
        __syncthreads();
        int off = (wid > 0) ? wsum[wid - 1] : 0;
        v += off + carry;
        if (i < n) rp[i + 1] = v;
        carry += wsum[15];
        __syncthreads();
    }
}

__global__ void k_copyofs(const int* __restrict__ rowptr, int* __restrict__ wofs, int n) {
    int i = blockIdx.x * blockDim.x + threadIdx.x;
    if (i < 3 * n) {
        int r = i / n, v = i - r * n;
        wofs[i] = rowptr[r * (n + 1) + v];
    }
}

__global__ void k_scatter(const int* __restrict__ src, const int* __restrict__ dst,
                          int* __restrict__ wofs, int* __restrict__ csrc, int nE, int n) {
    int r = blockIdx.y;
    int e = blockIdx.x * blockDim.x + threadIdx.x;
    if (e < nE) {
        int d = dst[r * nE + e];
        int pos = atomicAdd(&wofs[r * n + d], 1);
        csrc[(size_t)r * nE + pos] = src[r * nE + e];
    }
}

// ---------------- W prep: f32 [k][col] -> bf16 [col][k ^ ((col&7)<<3)] ----------------
__global__ void k_wprep(const float* __restrict__ Ws, short* __restrict__ Wt) {
    int i = blockIdx.x * blockDim.x + threadIdx.x;
    if (i < 6 * 16384) {
        int lr = i >> 14, rem = i & 16383, k = rem >> 7, col = rem & 127;
        Wt[lr * 16384 + col * 128 + (k ^ ((col & 7) << 3))] = f2bf(Ws[i]);
    }
}

// ---------------- f32 -> bf16 bulk convert ----------------
__global__ void k_cvt(const float* __restrict__ in, short* __restrict__ out, int n) {
    int i = blockIdx.x * blockDim.x + threadIdx.x;
    int stride = gridDim.x * blockDim.x;
    for (int base = i * 8; base < n; base += stride * 8) {
        float4 x = *(const float4*)(in + base);
        float4 y = *(const float4*)(in + base + 4);
        short8v o;
        o[0] = f2bf(x.x); o[1] = f2bf(x.y); o[2] = f2bf(x.z); o[3] = f2bf(x.w);
        o[4] = f2bf(y.x); o[5] = f2bf(y.y); o[6] = f2bf(y.z); o[7] = f2bf(y.w);
        *(short8v*)(out + base) = o;
    }
}

// ---------------- MFMA GEMM: out[N,128] = A(bf16)[N,128] x W(bf16)[128,128], fused el/er ----------------
// block = 256 (4 waves); each block does 128 rows; wave w: rows 32w..32w+31 (2 row-blocks of 16)
__global__ __launch_bounds__(256) void k_gemm(const short* __restrict__ Abf,
                                              const short* __restrict__ Wt,
                                              const float* __restrict__ al,
                                              const float* __restrict__ ar,
                                              float* __restrict__ outF,
                                              float4* __restrict__ elr, int nrows) {
    __shared__ __align__(16) short Wl[128 * 128];
    int tid = threadIdx.x;
    {   // linear 32 KB stage (layout already swizzled in global)
        const float4* srcv = (const float4*)Wt;
        float4* dstv = (float4*)Wl;
        #pragma unroll
        for (int i = 0; i < 8; i++) dstv[tid + i * 256] = srcv[tid + i * 256];
    }
    int lane = tid & 63, wid = tid >> 6;
    int q = lane >> 4, j = lane & 15;
    int rowbase = blockIdx.x * 128 + wid * 32;

    float alv[8], arv[8];
    #pragma unroll
    for (int cb = 0; cb < 8; cb++) { alv[cb] = al[cb * 16 + j]; arv[cb] = ar[cb * 16 + j]; }

    // A fragments: lane holds row (j), k = 32*kk + 8*q + 0..7
    short8v a[2][4];
    #pragma unroll
    for (int rb = 0; rb < 2; rb++) {
        int row = rowbase + rb * 16 + j;
        const short* ap = Abf + (size_t)row * 128 + q * 8;
        bool ok = row < nrows;
        #pragma unroll
        for (int kk = 0; kk < 4; kk++)
            a[rb][kk] = ok ? *(const short8v*)(ap + kk * 32) : (short8v)0;
    }
    __syncthreads();

    f32x4 acc[2][8] = {};
    #pragma unroll
    for (int cb = 0; cb < 8; cb++) {
        int col = cb * 16 + j;
        const short* wp = Wl + col * 128;
        int sw = (col & 7) << 3;
        #pragma unroll
        for (int kk = 0; kk < 4; kk++) {
            short8v b = *(const short8v*)(wp + ((kk * 32 + q * 8) ^ sw));
            acc[0][cb] = __builtin_amdgcn_mfma_f32_16x16x32_bf16(a[0][kk], b, acc[0][cb], 0, 0, 0);
            acc[1][cb] = __builtin_amdgcn_mfma_f32_16x16x32_bf16(a[1][kk], b, acc[1][cb], 0, 0, 0);
        }
    }

    // C store: lane holds col = 16*cb + j, rows q*4+reg within row-block
    #pragma unroll
    for (int rb = 0; rb < 2; rb++) {
        int row0 = rowbase + rb * 16 + q * 4;
        #pragma unroll
        for (int reg = 0; reg < 4; reg++) {
            int row = row0 + reg;
            if (row < nrows) {
                float* op = outF + (size_t)row * 128 + j;
                #pragma unroll
                for (int cb = 0; cb < 8; cb++) op[cb * 16] = acc[rb][cb][reg];
            }
        }
    }

    // fused el/er: dot over cols then 16-lane butterfly
    #pragma unroll
    for (int rb = 0; rb < 2; rb++) {
        float e0[4], e1[4], r0[4], r1[4];
        #pragma unroll
        for (int reg = 0; reg < 4; reg++) {
            float se0 = 0.f, se1 = 0.f, sr0 = 0.f, sr1 = 0.f;
            #pragma unroll
            for (int cb = 0; cb < 4; cb++) {
                se0 += acc[rb][cb][reg] * alv[cb];
                sr0 += acc[rb][cb][reg] * arv[cb];
                se1 += acc[rb][cb + 4][reg] * alv[cb + 4];
                sr1 += acc[rb][cb + 4][reg] * arv[cb + 4];
            }
            #pragma unroll
            for (int off = 1; off < 16; off <<= 1) {
                se0 += __shfl_xor(se0, off);
                se1 += __shfl_xor(se1, off);
                sr0 += __shfl_xor(sr0, off);
                sr1 += __shfl_xor(sr1, off);
            }
            e0[reg] = se0; e1[reg] = se1; r0[reg] = sr0; r1[reg] = sr1;
        }
        if (j < 4) {
            int row = rowbase + rb * 16 + q * 4 + j;
            if (row < nrows) {
                float4 v;
                v.x = j == 0 ? e0[0] : j == 1 ? e0[1] : j == 2 ? e0[2] : e0[3];
                v.y = j == 0 ? e1[0] : j == 1 ? e1[1] : j == 2 ? e1[2] : e1[3];
                v.z = j == 0 ? r0[0] : j == 1 ? r0[1] : j == 2 ? r0[2] : r0[3];
                v.w = j == 0 ? r1[0] : j == 1 ? r1[1] : j == 2 ? r1[2] : r1[3];
                elr[row] = v;
            }
        }
    }
}

// ---------------- per-node softmax + gather-aggregate ----------------
__global__ __launch_bounds__(256) void k_agg(const float* __restrict__ feat,
                                             const float4* __restrict__ elr,
                                             const int* __restrict__ rowptr,
                                             const int* __restrict__ csrc,
                                             const float* __restrict__ bias,
                                             float* __restrict__ acc, int nrows, int add) {
    int wid = threadIdx.x >> 6, lane = threadIdx.x & 63;
    int v = (blockIdx.x << 2) + wid;
    if (v >= nrows) return;
    int beg = rowptr[v], end = rowptr[v + 1];
    float4 ev = elr[v];
    float m0 = -1e30f, m1 = -1e30f;
    for (int i = beg; i < end; i++) {
        int s = csrc[i];
        float4 es = elr[s];
        float e0 = es.x + ev.z; e0 = e0 >= 0.f ? e0 : NEG_SLOPE * e0;
        float e1 = es.y + ev.w; e1 = e1 >= 0.f ? e1 : NEG_SLOPE * e1;
        m0 = fmaxf(m0, e0); m1 = fmaxf(m1, e1);
    }
    float s0 = 0.f, s1 = 0.f, a0 = 0.f, a1 = 0.f;
    for (int i = beg; i < end; i++) {
        int s = csrc[i];
        float4 es = elr[s];
        float e0 = es.x + ev.z; e0 = e0 >= 0.f ? e0 : NEG_SLOPE * e0;
        float e1 = es.y + ev.w; e1 = e1 >= 0.f ? e1 : NEG_SLOPE * e1;
        float p0 = __expf(e0 - m0), p1 = __expf(e1 - m1);
        s0 += p0; s1 += p1;
        a0 += p0 * feat[(size_t)s * 128 + lane];
        a1 += p1 * feat[(size_t)s * 128 + 64 + lane];
    }
    float i0 = s0 > 0.f ? 1.0f / s0 : 0.f;
    float i1 = s1 > 0.f ? 1.0f / s1 : 0.f;
    float r0 = a0 * i0 + bias[lane];
    float r1 = a1 * i1 + bias[64 + lane];
    size_t base = (size_t)v * 128 + lane;
    if (add) { acc[base] += r0; acc[base + 64] += r1; }
    else     { acc[base]  = r0; acc[base + 64]  = r1; }
}

// ---------------- relu: f32 in, optional f32 out + optional bf16 out ----------------
__global__ void k_relu(const float4* __restrict__ in, float4* __restrict__ outF,
                       short* __restrict__ outB, int n4) {
    for (int i = blockIdx.x * blockDim.x + threadIdx.x; i < n4; i += gridDim.x * blockDim.x) {
        float4 v = in[i];
        v.x = fmaxf(v.x, 0.f); v.y = fmaxf(v.y, 0.f);
        v.z = fmaxf(v.z, 0.f); v.w = fmaxf(v.w, 0.f);
        if (outF) outF[i] = v;
        if (outB) {
            short4v o;
            o[0] = f2bf(v.x); o[1] = f2bf(v.y); o[2] = f2bf(v.z); o[3] = f2bf(v.w);
            *(short4v*)(outB + (size_t)i * 4) = o;
        }
    }
}

// ---------------- BN stats ----------------
__global__ void k_bnstat(const float* __restrict__ h, float* __restrict__ sums, int nrows) {
    int ch = threadIdx.x & 127, half = threadIdx.x >> 7;
    float s = 0.f, s2 = 0.f;
    for (int row = blockIdx.x * 2 + half; row < nrows; row += gridDim.x * 2) {
        float x = h[(size_t)row * 128 + ch];
        s += x; s2 += x * x;
    }
    atomicAdd(&sums[ch], s);
    atomicAdd(&sums[128 + ch], s2);
}

// ---------------- BN-normalize + classifier GEMM [N,128]x[128,64] ----------------
__global__ __launch_bounds__(256) void k_clf(const float* __restrict__ h,
                                             const float* __restrict__ sums,
                                             const float* __restrict__ bn_w,
                                             const float* __restrict__ bn_b,
                                             const float* __restrict__ Wc,
                                             const float* __restrict__ cb,
                                             float* __restrict__ out, int nrows) {
    __shared__ float Wt[64][128];
    __shared__ float2 bnp[128];
    __shared__ float hrow[4][128];
    int tid = threadIdx.x;
    for (int idx = tid; idx < 2048; idx += 256) {
        int k = idx >> 4, c4 = (idx & 15) << 2;
        float4 w = *(const float4*)(Wc + k * 64 + c4);
        int kk = k >> 2, kr = k & 3;
        Wt[c4 + 0][((kk ^ ((c4 + 0) & 7)) << 2) + kr] = w.x;
        Wt[c4 + 1][((kk ^ ((c4 + 1) & 7)) << 2) + kr] = w.y;
        Wt[c4 + 2][((kk ^ ((c4 + 2) & 7)) << 2) + kr] = w.z;
        Wt[c4 + 3][((kk ^ ((c4 + 3) & 7)) << 2) + kr] = w.w;
    }
    if (tid < 128) {
        float mu = sums[tid] / (float)nrows;
        float var = sums[128 + tid] / (float)nrows - mu * mu;
        float rs = rsqrtf(var + 1e-5f);
        float sc = bn_w[tid] * rs;
        bnp[tid] = make_float2(sc, bn_b[tid] - mu * sc);
    }
    __syncthreads();
    int wid = tid >> 6, lane = tid & 63;
    float cbv = cb[lane];
    for (int row = (blockIdx.x << 2) + wid; row < nrows; row += gridDim.x << 2) {
        float x0 = h[(size_t)row * 128 + lane];
        float x1 = h[(size_t)row * 128 + 64 + lane];
        hrow[wid][lane] = x0 * bnp[lane].x + bnp[lane].y;
        hrow[wid][64 + lane] = x1 * bnp[64 + lane].x + bnp[64 + lane].y;
        float acc = cbv;
        #pragma unroll
        for (int kk = 0; kk < 32; kk++) {
            float4 hv = *(float4*)&hrow[wid][kk << 2];
            float4 wv = *(float4*)&Wt[lane][(kk ^ (lane & 7)) << 2];
            acc += hv.x * wv.x + hv.y * wv.y + hv.z * wv.z + hv.w * wv.w;
        }
        out[(size_t)row * 64 + lane] = acc;
    }
}

// ---------------- launch ----------------

extern "C" void kernel_launch(void* const* d_in, const int* in_sizes, int n_in,
                              void* d_out, int out_size, void* d_ws, size_t ws_size,
                              hipStream_t stream) {
    (void)in_sizes; (void)n_in; (void)out_size; (void)ws_size;
    const float* feat_in = (const float*)d_in[0];
    const float* Ws      = (const float*)d_in[1];
    const float* als     = (const float*)d_in[2];
    const float* ars     = (const float*)d_in[3];
    const float* bs      = (const float*)d_in[4];
    const float* bn_w    = (const float*)d_in[5];
    const float* bn_b    = (const float*)d_in[6];
    const float* clf_W   = (const float*)d_in[7];
    const float* clf_b   = (const float*)d_in[8];
    const int*   src     = (const int*)d_in[9];
    const int*   dst     = (const int*)d_in[10];
    float* out = (float*)d_out;

    const int N = N_NODES, E = N_EDGES;
    char* p = (char*)d_ws;
    auto carve = [&](size_t bytes) { char* q = p; p += (bytes + 255) & ~255ULL; return q; };
    int*    wofs   = (int*)carve((size_t)3 * N * 4);
    int*    rowptr = (int*)carve((size_t)3 * (N + 1) * 4);
    int*    csrc   = (int*)carve((size_t)3 * E * 4);
    float4* elr    = (float4*)carve((size_t)N * 16);
    float*  bnsum  = (float*)carve(256 * 4);
    short*  Wtg    = (short*)carve((size_t)6 * 16384 * 2);
    short*  hbf    = (short*)carve((size_t)N * 128 * 2);
    float*  featb  = (float*)carve((size_t)N * 128 * 4);
    float*  accb   = (float*)carve((size_t)N * 128 * 4);

    // weight prep + input conversion
    k_wprep<<<(6 * 16384 + 255) / 256, 256, 0, stream>>>(Ws, Wtg);
    k_cvt<<<2048, 256, 0, stream>>>(feat_in, hbf, N * 128);

    // CSR build (reused across both layers)
    hipMemsetAsync(wofs, 0, (size_t)3 * N * 4, stream);
    dim3 ge((E + 255) / 256, 3);
    k_hist<<<ge, 256, 0, stream>>>(dst, wofs, E, N);
    k_scan<<<3, 1024, 0, stream>>>(wofs, rowptr, N);
    k_copyofs<<<(3 * N + 255) / 256, 256, 0, stream>>>(rowptr, wofs, N);
    k_scatter<<<ge, 256, 0, stream>>>(src, dst, wofs, csrc, E, N);

    for (int l = 0; l < 2; l++) {
        for (int r = 0; r < 3; r++) {
            int lr = l * 3 + r;
            k_gemm<<<(N + 127) / 128, 256, 0, stream>>>(hbf, Wtg + (size_t)lr * 16384,
                                                        als + lr * 128, ars + lr * 128,
                                                        featb, elr, N);
            k_agg<<<(N + 3) / 4, 256, 0, stream>>>(featb, elr, rowptr + r * (N + 1),
                                                   csrc + (size_t)r * E, bs + lr * 128,
                                                   accb, N, r);
        }
        if (l == 0)
            k_relu<<<2048, 256, 0, stream>>>((const float4*)accb, nullptr, hbf, N * 32);
        else
            k_relu<<<2048, 256, 0, stream>>>((const float4*)accb, (float4*)featb, nullptr, N * 32);
    }

    hipMemsetAsync(bnsum, 0, 256 * 4, stream);
    k_bnstat<<<2048, 256, 0, stream>>>(featb, bnsum, N);
    k_clf<<<1024, 256, 0, stream>>>(featb, bnsum, bn_w, bn_b, clf_W, clf_b, out, N);
}

// Round 3
// 1038.476 us; speedup vs baseline: 2.0920x; 1.2697x over previous
//
#include <hip/hip_runtime.h>
#include <hip/hip_bf16.h>

#define N_NODES 100000
#define N_EDGES 500000
#define HID 128
#define NEG_SLOPE 0.2f

typedef __attribute__((ext_vector_type(8))) short short8v;
typedef __attribute__((ext_vector_type(4))) short short4v;
typedef __attribute__((ext_vector_type(4))) float f32x4;

__device__ __forceinline__ short f2bf(float x) {
    union { float f; unsigned u; } v; v.f = x;
    unsigned r = v.u + 0x7fff + ((v.u >> 16) & 1);  // RNE
    return (short)(r >> 16);
}

// ---------------- CSR build ----------------

__global__ void k_hist(const int* __restrict__ dst, int* __restrict__ cnt, int nE, int n) {
    int r = blockIdx.y;
    int e = blockIdx.x * blockDim.x + threadIdx.x;
    if (e < nE) atomicAdd(&cnt[r * n + dst[r * nE + e]], 1);
}

__global__ __launch_bounds__(1024) void k_scan(const int* __restrict__ cnt,
                                               int* __restrict__ rowptr, int n) {
    int r = blockIdx.x;
    const int* c = cnt + r * n;
    int* rp = rowptr + r * (n + 1);
    __shared__ int wsum[16];
    int tid = threadIdx.x, lane = tid & 63, wid = tid >> 6;
    if (tid == 0) rp[0] = 0;
    int carry = 0;
    for (int base = 0; base < n; base += 1024) {
        int i = base + tid;
        int v = (i < n) ? c[i] : 0;
        #pragma unroll
        for (int d = 1; d < 64; d <<= 1) {
            int t = __shfl_up(v, d);
            if (lane >= d) v += t;
        }
        if (lane == 63) wsum[wid] = v;
        __syncthreads();
        if (wid == 0) {
            int s = (lane < 16) ? wsum[lane] : 0;
            #pragma unroll
            for (int d = 1; d < 16; d <<= 1) {
                int t = __shfl_up(s, d);
                if (lane >= d) s += t;
            }
            if (lane < 16) wsum[lane] = s;
        }
        __syncthreads();
        int off = (wid > 0) ? wsum[wid - 1] : 0;
        v += off + carry;
        if (i < n) rp[i + 1] = v;
        carry += wsum[15];
        __syncthreads();
    }
}

__global__ void k_copyofs(const int* __restrict__ rowptr, int* __restrict__ wofs, int n) {
    int i = blockIdx.x * blockDim.x + threadIdx.x;
    if (i < 3 * n) {
        int r = i / n, v = i - r * n;
        wofs[i] = rowptr[r * (n + 1) + v];
    }
}

__global__ void k_scatter(const int* __restrict__ src, const int* __restrict__ dst,
                          int* __restrict__ wofs, int* __restrict__ csrc, int nE, int n) {
    int r = blockIdx.y;
    int e = blockIdx.x * blockDim.x + threadIdx.x;
    if (e < nE) {
        int d = dst[r * nE + e];
        int pos = atomicAdd(&wofs[r * n + d], 1);
        csrc[(size_t)r * nE + pos] = src[r * nE + e];
    }
}

// ---------------- W prep: f32 [k][col] -> bf16 [col][k ^ ((col&7)<<3)] ----------------
__global__ void k_wprep(const float* __restrict__ Ws, short* __restrict__ Wt) {
    int i = blockIdx.x * blockDim.x + threadIdx.x;
    if (i < 6 * 16384) {
        int lr = i >> 14, rem = i & 16383, k = rem >> 7, col = rem & 127;
        Wt[lr * 16384 + col * 128 + (k ^ ((col & 7) << 3))] = f2bf(Ws[i]);
    }
}

// ---------------- f32 -> bf16 bulk convert ----------------
__global__ void k_cvt(const float* __restrict__ in, short* __restrict__ out, int n) {
    int i = blockIdx.x * blockDim.x + threadIdx.x;
    int stride = gridDim.x * blockDim.x;
    for (int base = i * 8; base < n; base += stride * 8) {
        float4 x = *(const float4*)(in + base);
        float4 y = *(const float4*)(in + base + 4);
        short8v o;
        o[0] = f2bf(x.x); o[1] = f2bf(x.y); o[2] = f2bf(x.z); o[3] = f2bf(x.w);
        o[4] = f2bf(y.x); o[5] = f2bf(y.y); o[6] = f2bf(y.z); o[7] = f2bf(y.w);
        *(short8v*)(out + base) = o;
    }
}

// ---------------- MFMA GEMM: out[N,128] = A(bf16)[N,128] x W(bf16)[128,128], fused el/er ----------------
__global__ __launch_bounds__(256) void k_gemm(const short* __restrict__ Abf,
                                              const short* __restrict__ Wt,
                                              const float* __restrict__ al,
                                              const float* __restrict__ ar,
                                              float* __restrict__ outF,
                                              float4* __restrict__ elr, int nrows) {
    __shared__ __align__(16) short Wl[128 * 128];
    int tid = threadIdx.x;
    {   // linear 32 KB stage (layout already swizzled in global)
        const float4* srcv = (const float4*)Wt;
        float4* dstv = (float4*)Wl;
        #pragma unroll
        for (int i = 0; i < 8; i++) dstv[tid + i * 256] = srcv[tid + i * 256];
    }
    int lane = tid & 63, wid = tid >> 6;
    int q = lane >> 4, j = lane & 15;
    int rowbase = blockIdx.x * 128 + wid * 32;

    float alv[8], arv[8];
    #pragma unroll
    for (int cb = 0; cb < 8; cb++) { alv[cb] = al[cb * 16 + j]; arv[cb] = ar[cb * 16 + j]; }

    short8v a[2][4];
    #pragma unroll
    for (int rb = 0; rb < 2; rb++) {
        int row = rowbase + rb * 16 + j;
        const short* ap = Abf + (size_t)row * 128 + q * 8;
        bool ok = row < nrows;
        #pragma unroll
        for (int kk = 0; kk < 4; kk++)
            a[rb][kk] = ok ? *(const short8v*)(ap + kk * 32) : (short8v)0;
    }
    __syncthreads();

    f32x4 acc[2][8] = {};
    #pragma unroll
    for (int cb = 0; cb < 8; cb++) {
        int col = cb * 16 + j;
        const short* wp = Wl + col * 128;
        int sw = (col & 7) << 3;
        #pragma unroll
        for (int kk = 0; kk < 4; kk++) {
            short8v b = *(const short8v*)(wp + ((kk * 32 + q * 8) ^ sw));
            acc[0][cb] = __builtin_amdgcn_mfma_f32_16x16x32_bf16(a[0][kk], b, acc[0][cb], 0, 0, 0);
            acc[1][cb] = __builtin_amdgcn_mfma_f32_16x16x32_bf16(a[1][kk], b, acc[1][cb], 0, 0, 0);
        }
    }

    #pragma unroll
    for (int rb = 0; rb < 2; rb++) {
        int row0 = rowbase + rb * 16 + q * 4;
        #pragma unroll
        for (int reg = 0; reg < 4; reg++) {
            int row = row0 + reg;
            if (row < nrows) {
                float* op = outF + (size_t)row * 128 + j;
                #pragma unroll
                for (int cb = 0; cb < 8; cb++) op[cb * 16] = acc[rb][cb][reg];
            }
        }
    }

    // fused el/er
    #pragma unroll
    for (int rb = 0; rb < 2; rb++) {
        float e0[4], e1[4], r0[4], r1[4];
        #pragma unroll
        for (int reg = 0; reg < 4; reg++) {
            float se0 = 0.f, se1 = 0.f, sr0 = 0.f, sr1 = 0.f;
            #pragma unroll
            for (int cb = 0; cb < 4; cb++) {
                se0 += acc[rb][cb][reg] * alv[cb];
                sr0 += acc[rb][cb][reg] * arv[cb];
                se1 += acc[rb][cb + 4][reg] * alv[cb + 4];
                sr1 += acc[rb][cb + 4][reg] * arv[cb + 4];
            }
            #pragma unroll
            for (int off = 1; off < 16; off <<= 1) {
                se0 += __shfl_xor(se0, off);
                se1 += __shfl_xor(se1, off);
                sr0 += __shfl_xor(sr0, off);
                sr1 += __shfl_xor(sr1, off);
            }
            e0[reg] = se0; e1[reg] = se1; r0[reg] = sr0; r1[reg] = sr1;
        }
        if (j < 4) {
            int row = rowbase + rb * 16 + q * 4 + j;
            if (row < nrows) {
                float4 v;
                v.x = j == 0 ? e0[0] : j == 1 ? e0[1] : j == 2 ? e0[2] : e0[3];
                v.y = j == 0 ? e1[0] : j == 1 ? e1[1] : j == 2 ? e1[2] : e1[3];
                v.z = j == 0 ? r0[0] : j == 1 ? r0[1] : j == 2 ? r0[2] : r0[3];
                v.w = j == 0 ? r1[0] : j == 1 ? r1[1] : j == 2 ? r1[2] : r1[3];
                elr[row] = v;
            }
        }
    }
}

// ---------------- softmax (node-per-thread): write unnormalized p per edge + 1/sum per node ----------------
__global__ __launch_bounds__(256) void k_soft(const float4* __restrict__ elr,
                                              const int* __restrict__ rowptr,
                                              const int* __restrict__ csrc,
                                              float2* __restrict__ palpha,
                                              float2* __restrict__ nsum, int nrows) {
    int v = blockIdx.x * blockDim.x + threadIdx.x;
    if (v >= nrows) return;
    int beg = rowptr[v], end = rowptr[v + 1];
    float4 ev = elr[v];
    float m0 = -1e30f, m1 = -1e30f;
    for (int i = beg; i < end; i++) {
        int s = csrc[i];
        float4 es = elr[s];
        float e0 = es.x + ev.z; e0 = e0 >= 0.f ? e0 : NEG_SLOPE * e0;
        float e1 = es.y + ev.w; e1 = e1 >= 0.f ? e1 : NEG_SLOPE * e1;
        m0 = fmaxf(m0, e0); m1 = fmaxf(m1, e1);
    }
    float s0 = 0.f, s1 = 0.f;
    for (int i = beg; i < end; i++) {
        int s = csrc[i];
        float4 es = elr[s];
        float e0 = es.x + ev.z; e0 = e0 >= 0.f ? e0 : NEG_SLOPE * e0;
        float e1 = es.y + ev.w; e1 = e1 >= 0.f ? e1 : NEG_SLOPE * e1;
        float p0 = __expf(e0 - m0), p1 = __expf(e1 - m1);
        s0 += p0; s1 += p1;
        palpha[i] = make_float2(p0, p1);
    }
    nsum[v] = make_float2(s0 > 0.f ? 1.0f / s0 : 0.f, s1 > 0.f ? 1.0f / s1 : 0.f);
}

// ---------------- aggregate (wave-per-node, single pass, lane-prefetched edge metadata) ----------------
__global__ __launch_bounds__(256) void k_agg(const float* __restrict__ feat,
                                             const float2* __restrict__ palpha,
                                             const float2* __restrict__ nsum,
                                             const int* __restrict__ rowptr,
                                             const int* __restrict__ csrc,
                                             const float* __restrict__ bias,
                                             float* __restrict__ acc, int nrows, int add) {
    int wid = threadIdx.x >> 6, lane = threadIdx.x & 63;
    int v = (blockIdx.x << 2) + wid;
    if (v >= nrows) return;
    int beg = rowptr[v], end = rowptr[v + 1];
    float a0 = 0.f, a1 = 0.f;
    for (int base = beg; base < end; base += 64) {
        int idx = base + lane;
        int sv = 0;
        float2 pv = make_float2(0.f, 0.f);
        if (idx < end) { sv = csrc[idx]; pv = palpha[idx]; }
        int cnt = min(64, end - base);
        for (int jj = 0; jj < cnt; jj++) {
            int s = __shfl(sv, jj);
            float p0 = __shfl(pv.x, jj);
            float p1 = __shfl(pv.y, jj);
            const float* fp = feat + (size_t)s * 128 + lane;
            a0 += p0 * fp[0];
            a1 += p1 * fp[64];
        }
    }
    float2 inv = nsum[v];
    float r0 = a0 * inv.x + bias[lane];
    float r1 = a1 * inv.y + bias[64 + lane];
    size_t basep = (size_t)v * 128 + lane;
    if (add) { acc[basep] += r0; acc[basep + 64] += r1; }
    else     { acc[basep]  = r0; acc[basep + 64]  = r1; }
}

// ---------------- relu: f32 in, optional f32 out + optional bf16 out ----------------
__global__ void k_relu(const float4* __restrict__ in, float4* __restrict__ outF,
                       short* __restrict__ outB, int n4) {
    for (int i = blockIdx.x * blockDim.x + threadIdx.x; i < n4; i += gridDim.x * blockDim.x) {
        float4 v = in[i];
        v.x = fmaxf(v.x, 0.f); v.y = fmaxf(v.y, 0.f);
        v.z = fmaxf(v.z, 0.f); v.w = fmaxf(v.w, 0.f);
        if (outF) outF[i] = v;
        if (outB) {
            short4v o;
            o[0] = f2bf(v.x); o[1] = f2bf(v.y); o[2] = f2bf(v.z); o[3] = f2bf(v.w);
            *(short4v*)(outB + (size_t)i * 4) = o;
        }
    }
}

// ---------------- BN stats ----------------
__global__ void k_bnstat(const float* __restrict__ h, float* __restrict__ sums, int nrows) {
    int ch = threadIdx.x & 127, half = threadIdx.x >> 7;
    float s = 0.f, s2 = 0.f;
    for (int row = blockIdx.x * 2 + half; row < nrows; row += gridDim.x * 2) {
        float x = h[(size_t)row * 128 + ch];
        s += x; s2 += x * x;
    }
    atomicAdd(&sums[ch], s);
    atomicAdd(&sums[128 + ch], s2);
}

// ---------------- BN-normalize + classifier GEMM [N,128]x[128,64] ----------------
__global__ __launch_bounds__(256) void k_clf(const float* __restrict__ h,
                                             const float* __restrict__ sums,
                                             const float* __restrict__ bn_w,
                                             const float* __restrict__ bn_b,
                                             const float* __restrict__ Wc,
                                             const float* __restrict__ cb,
                                             float* __restrict__ out, int nrows) {
    __shared__ float Wt[64][128];
    __shared__ float2 bnp[128];
    __shared__ float hrow[4][128];
    int tid = threadIdx.x;
    for (int idx = tid; idx < 2048; idx += 256) {
        int k = idx >> 4, c4 = (idx & 15) << 2;
        float4 w = *(const float4*)(Wc + k * 64 + c4);
        int kk = k >> 2, kr = k & 3;
        Wt[c4 + 0][((kk ^ ((c4 + 0) & 7)) << 2) + kr] = w.x;
        Wt[c4 + 1][((kk ^ ((c4 + 1) & 7)) << 2) + kr] = w.y;
        Wt[c4 + 2][((kk ^ ((c4 + 2) & 7)) << 2) + kr] = w.z;
        Wt[c4 + 3][((kk ^ ((c4 + 3) & 7)) << 2) + kr] = w.w;
    }
    if (tid < 128) {
        float mu = sums[tid] / (float)nrows;
        float var = sums[128 + tid] / (float)nrows - mu * mu;
        float rs = rsqrtf(var + 1e-5f);
        float sc = bn_w[tid] * rs;
        bnp[tid] = make_float2(sc, bn_b[tid] - mu * sc);
    }
    __syncthreads();
    int wid = tid >> 6, lane = tid & 63;
    float cbv = cb[lane];
    for (int row = (blockIdx.x << 2) + wid; row < nrows; row += gridDim.x << 2) {
        float x0 = h[(size_t)row * 128 + lane];
        float x1 = h[(size_t)row * 128 + 64 + lane];
        hrow[wid][lane] = x0 * bnp[lane].x + bnp[lane].y;
        hrow[wid][64 + lane] = x1 * bnp[64 + lane].x + bnp[64 + lane].y;
        float acc = cbv;
        #pragma unroll
        for (int kk = 0; kk < 32; kk++) {
            float4 hv = *(float4*)&hrow[wid][kk << 2];
            float4 wv = *(float4*)&Wt[lane][(kk ^ (lane & 7)) << 2];
            acc += hv.x * wv.x + hv.y * wv.y + hv.z * wv.z + hv.w * wv.w;
        }
        out[(size_t)row * 64 + lane] = acc;
    }
}

// ---------------- launch ----------------

extern "C" void kernel_launch(void* const* d_in, const int* in_sizes, int n_in,
                              void* d_out, int out_size, void* d_ws, size_t ws_size,
                              hipStream_t stream) {
    (void)in_sizes; (void)n_in; (void)out_size; (void)ws_size;
    const float* feat_in = (const float*)d_in[0];
    const float* Ws      = (const float*)d_in[1];
    const float* als     = (const float*)d_in[2];
    const float* ars     = (const float*)d_in[3];
    const float* bs      = (const float*)d_in[4];
    const float* bn_w    = (const float*)d_in[5];
    const float* bn_b    = (const float*)d_in[6];
    const float* clf_W   = (const float*)d_in[7];
    const float* clf_b   = (const float*)d_in[8];
    const int*   src     = (const int*)d_in[9];
    const int*   dst     = (const int*)d_in[10];
    float* out = (float*)d_out;

    const int N = N_NODES, E = N_EDGES;
    char* p = (char*)d_ws;
    auto carve = [&](size_t bytes) { char* q = p; p += (bytes + 255) & ~255ULL; return q; };
    int*    wofs   = (int*)carve((size_t)3 * N * 4);
    int*    rowptr = (int*)carve((size_t)3 * (N + 1) * 4);
    int*    csrc   = (int*)carve((size_t)3 * E * 4);
    float4* elr    = (float4*)carve((size_t)N * 16);
    float2* palpha = (float2*)carve((size_t)E * 8);
    float2* nsum   = (float2*)carve((size_t)N * 8);
    float*  bnsum  = (float*)carve(256 * 4);
    short*  Wtg    = (short*)carve((size_t)6 * 16384 * 2);
    short*  hbf    = (short*)carve((size_t)N * 128 * 2);
    float*  featb  = (float*)carve((size_t)N * 128 * 4);
    float*  accb   = (float*)carve((size_t)N * 128 * 4);

    // weight prep + input conversion
    k_wprep<<<(6 * 16384 + 255) / 256, 256, 0, stream>>>(Ws, Wtg);
    k_cvt<<<2048, 256, 0, stream>>>(feat_in, hbf, N * 128);

    // CSR build (reused across both layers)
    hipMemsetAsync(wofs, 0, (size_t)3 * N * 4, stream);
    dim3 ge((E + 255) / 256, 3);
    k_hist<<<ge, 256, 0, stream>>>(dst, wofs, E, N);
    k_scan<<<3, 1024, 0, stream>>>(wofs, rowptr, N);
    k_copyofs<<<(3 * N + 255) / 256, 256, 0, stream>>>(rowptr, wofs, N);
    k_scatter<<<ge, 256, 0, stream>>>(src, dst, wofs, csrc, E, N);

    for (int l = 0; l < 2; l++) {
        for (int r = 0; r < 3; r++) {
            int lr = l * 3 + r;
            const int* rp = rowptr + r * (N + 1);
            const int* cs = csrc + (size_t)r * E;
            k_gemm<<<(N + 127) / 128, 256, 0, stream>>>(hbf, Wtg + (size_t)lr * 16384,
                                                        als + lr * 128, ars + lr * 128,
                                                        featb, elr, N);
            k_soft<<<(N + 255) / 256, 256, 0, stream>>>(elr, rp, cs, palpha, nsum, N);
            k_agg<<<(N + 3) / 4, 256, 0, stream>>>(featb, palpha, nsum, rp, cs,
                                                   bs + lr * 128, accb, N, r);
        }
        if (l == 0)
            k_relu<<<2048, 256, 0, stream>>>((const float4*)accb, nullptr, hbf, N * 32);
        else
            k_relu<<<2048, 256, 0, stream>>>((const float4*)accb, (float4*)featb, nullptr, N * 32);
    }

    hipMemsetAsync(bnsum, 0, 256 * 4, stream);
    k_bnstat<<<2048, 256, 0, stream>>>(featb, bnsum, N);
    k_clf<<<1024, 256, 0, stream>>>(featb, bnsum, bn_w, bn_b, clf_W, clf_b, out, N);
}

// Round 4
// 763.581 us; speedup vs baseline: 2.8451x; 1.3600x over previous
//
#include <hip/hip_runtime.h>
#include <hip/hip_bf16.h>

#define N_NODES 100000
#define N_EDGES 500000
#define HID 128
#define NEG_SLOPE 0.2f
#define NB 98           // buckets of 1024 nodes: ceil(100000/1024)

typedef __attribute__((ext_vector_type(8))) short short8v;
typedef __attribute__((ext_vector_type(4))) short short4v;
typedef __attribute__((ext_vector_type(4))) float f32x4;

__device__ __forceinline__ short f2bf(float x) {
    union { float f; unsigned u; } v; v.f = x;
    unsigned r = v.u + 0x7fff + ((v.u >> 16) & 1);  // RNE
    return (short)(r >> 16);
}
__device__ __forceinline__ float bflo(unsigned u) {
    union { unsigned x; float f; } c; c.x = u << 16; return c.f;
}
__device__ __forceinline__ float bfhi(unsigned u) {
    union { unsigned x; float f; } c; c.x = u & 0xffff0000u; return c.f;
}

// ---------------- CSR build: binned two-level sort ----------------

// bucket-level histogram (LDS-privatized, ~12k global atomics total)
__global__ __launch_bounds__(256) void k_bhist(const int* __restrict__ dst, int* __restrict__ bcnt) {
    int r = blockIdx.y, tid = threadIdx.x;
    int base = blockIdx.x * 4096;
    __shared__ int h[128];
    if (tid < 128) h[tid] = 0;
    __syncthreads();
    size_t eb = (size_t)r * N_EDGES;
    int lim = min(base + 4096, N_EDGES);
    for (int e = base + tid; e < lim; e += 256) atomicAdd(&h[dst[eb + e] >> 10], 1);
    __syncthreads();
    if (tid < NB && h[tid]) atomicAdd(&bcnt[r * NB + tid], h[tid]);
}

// scan bucket counts -> bptr (exclusive, per relation); init bcur
__global__ void k_bscan(const int* __restrict__ bcnt, int* __restrict__ bptr, int* __restrict__ bcur) {
    int r = blockIdx.x, lane = threadIdx.x;
    int carry = 0;
    for (int base = 0; base < NB; base += 64) {
        int i = base + lane;
        int c = (i < NB) ? bcnt[r * NB + i] : 0;
        int v = c;
        #pragma unroll
        for (int d = 1; d < 64; d <<= 1) { int t = __shfl_up(v, d); if (lane >= d) v += t; }
        int excl = carry + v - c;
        if (i < NB) { bptr[r * (NB + 1) + i] = excl; bcur[r * NB + i] = excl; }
        carry += __shfl(v, 63);
    }
    if (lane == 0) bptr[r * (NB + 1) + NB] = carry;
}

// bin edges into bucket regions of ebin as (dst,src) pairs; per-block LDS binning,
// bulk reservation per bucket -> writes are contiguous segments
__global__ __launch_bounds__(256) void k_bin(const int* __restrict__ src, const int* __restrict__ dst,
                                             int* __restrict__ bcur, uint2* __restrict__ ebin) {
    int r = blockIdx.y, tid = threadIdx.x;
    int base = blockIdx.x * 4096;
    __shared__ int cnt[128], incl[128], gb[128], wcur[128];
    __shared__ uint2 stage[4096];
    if (tid < 128) cnt[tid] = 0;
    __syncthreads();
    int myd[16], mys[16];
    size_t eb = (size_t)r * N_EDGES;
    #pragma unroll
    for (int i = 0; i < 16; i++) {
        int e = base + i * 256 + tid;
        if (e < N_EDGES) {
            int d = dst[eb + e];
            myd[i] = d; mys[i] = src[eb + e];
            atomicAdd(&cnt[d >> 10], 1);
        } else myd[i] = -1;
    }
    __syncthreads();
    if (tid < 128) incl[tid] = cnt[tid];
    __syncthreads();
    for (int d = 1; d < 128; d <<= 1) {
        int t = 0;
        if (tid < 128 && tid >= d) t = incl[tid - d];
        __syncthreads();
        if (tid < 128 && tid >= d) incl[tid] += t;
        __syncthreads();
    }
    if (tid < 128) {
        wcur[tid] = incl[tid] - cnt[tid];
        gb[tid] = (tid < NB && cnt[tid] > 0) ? atomicAdd(&bcur[r * NB + tid], cnt[tid]) : 0;
    }
    __syncthreads();
    #pragma unroll
    for (int i = 0; i < 16; i++) {
        if (myd[i] >= 0) {
            int bkt = myd[i] >> 10;
            int p = atomicAdd(&wcur[bkt], 1);
            stage[p] = make_uint2((unsigned)myd[i], (unsigned)mys[i]);
        }
    }
    __syncthreads();
    int tot = min(4096, N_EDGES - base);
    for (int i = tid; i < tot; i += 256) {
        uint2 u = stage[i];
        int bkt = (int)(u.x >> 10);
        int ex = incl[bkt] - cnt[bkt];
        ebin[eb + gb[bkt] + (i - ex)] = u;
    }
}

// per-bucket node histogram + local scan -> rowptr (no global atomics, coalesced writes)
__global__ __launch_bounds__(256) void k_nhist(const uint2* __restrict__ ebin,
                                               const int* __restrict__ bptr,
                                               int* __restrict__ rowptr) {
    int b = blockIdx.x, r = blockIdx.y, tid = threadIdx.x;
    __shared__ int cnt[1024];
    __shared__ int wsum[4];
    for (int i = tid; i < 1024; i += 256) cnt[i] = 0;
    __syncthreads();
    int es = bptr[r * (NB + 1) + b], ee = bptr[r * (NB + 1) + b + 1];
    size_t eb = (size_t)r * N_EDGES;
    for (int i = es + tid; i < ee; i += 256) atomicAdd(&cnt[ebin[eb + i].x & 1023], 1);
    __syncthreads();
    int b4 = tid * 4;
    int c0 = cnt[b4], c1 = cnt[b4 + 1], c2 = cnt[b4 + 2], c3 = cnt[b4 + 3];
    int ts = c0 + c1 + c2 + c3;
    int lane = tid & 63, wid = tid >> 6;
    int v = ts;
    #pragma unroll
    for (int d = 1; d < 64; d <<= 1) { int t = __shfl_up(v, d); if (lane >= d) v += t; }
    if (lane == 63) wsum[wid] = v;
    __syncthreads();
    int woff = 0;
    for (int w = 0; w < wid; w++) woff += wsum[w];
    int p = woff + v - ts;   // exclusive prefix for this thread's 4 nodes
    int node0 = b << 10;
    int rp = r * (N_NODES + 1);
    int nd;
    nd = node0 + b4;     if (nd < N_NODES) rowptr[rp + nd] = es + p; p += c0;
    nd = node0 + b4 + 1; if (nd < N_NODES) rowptr[rp + nd] = es + p; p += c1;
    nd = node0 + b4 + 2; if (nd < N_NODES) rowptr[rp + nd] = es + p; p += c2;
    nd = node0 + b4 + 3; if (nd < N_NODES) rowptr[rp + nd] = es + p;
    if (b == NB - 1 && tid == 0) rowptr[rp + N_NODES] = bptr[r * (NB + 1) + NB];
}

// per-bucket placement into CSR order, LDS-staged -> linear coalesced csrc writes
__global__ __launch_bounds__(256) void k_scat2(const uint2* __restrict__ ebin,
                                               const int* __restrict__ bptr,
                                               const int* __restrict__ rowptr,
                                               int* __restrict__ csrc) {
    int b = blockIdx.x, r = blockIdx.y, tid = threadIdx.x;
    __shared__ int cnt[1024];
    __shared__ int rloc[1024];
    __shared__ int stage[8192];
    int node0 = b << 10;
    int rp = r * (N_NODES + 1);
    int rs = rowptr[rp + node0];
    for (int i = tid; i < 1024; i += 256) {
        cnt[i] = 0;
        int nd = node0 + i; if (nd > N_NODES) nd = N_NODES;
        rloc[i] = rowptr[rp + nd] - rs;
    }
    __syncthreads();
    int es = bptr[r * (NB + 1) + b], ee = bptr[r * (NB + 1) + b + 1];
    int sz = ee - es;
    size_t eb = (size_t)r * N_EDGES;
    if (sz <= 8192) {
        for (int i = es + tid; i < ee; i += 256) {
            uint2 u = ebin[eb + i];
            int dl = u.x & 1023;
            int rk = atomicAdd(&cnt[dl], 1);
            stage[rloc[dl] + rk] = (int)u.y;
        }
        __syncthreads();
        for (int i = tid; i < sz; i += 256) csrc[eb + rs + i] = stage[i];
    } else {  // statistically unreachable fallback
        for (int i = es + tid; i < ee; i += 256) {
            uint2 u = ebin[eb + i];
            int dl = u.x & 1023;
            int rk = atomicAdd(&cnt[dl], 1);
            csrc[eb + rs + rloc[dl] + rk] = (int)u.y;
        }
    }
}

// ---------------- W prep: f32 [k][col] -> bf16 [col][k ^ ((col&7)<<3)] ----------------
__global__ void k_wprep(const float* __restrict__ Ws, short* __restrict__ Wt) {
    int i = blockIdx.x * blockDim.x + threadIdx.x;
    if (i < 6 * 16384) {
        int lr = i >> 14, rem = i & 16383, k = rem >> 7, col = rem & 127;
        Wt[lr * 16384 + col * 128 + (k ^ ((col & 7) << 3))] = f2bf(Ws[i]);
    }
}

// ---------------- f32 -> bf16 bulk convert ----------------
__global__ void k_cvt(const float* __restrict__ in, short* __restrict__ out, int n) {
    int i = blockIdx.x * blockDim.x + threadIdx.x;
    int stride = gridDim.x * blockDim.x;
    for (int base = i * 8; base < n; base += stride * 8) {
        float4 x = *(const float4*)(in + base);
        float4 y = *(const float4*)(in + base + 4);
        short8v o;
        o[0] = f2bf(x.x); o[1] = f2bf(x.y); o[2] = f2bf(x.z); o[3] = f2bf(x.w);
        o[4] = f2bf(y.x); o[5] = f2bf(y.y); o[6] = f2bf(y.z); o[7] = f2bf(y.w);
        *(short8v*)(out + base) = o;
    }
}

// ---------------- MFMA GEMM: bf16 out + fused el/er ----------------
__global__ __launch_bounds__(256) void k_gemm(const short* __restrict__ Abf,
                                              const short* __restrict__ Wt,
                                              const float* __restrict__ al,
                                              const float* __restrict__ ar,
                                              short* __restrict__ outB,
                                              float4* __restrict__ elr, int nrows) {
    __shared__ __align__(16) short Wl[128 * 128];
    int tid = threadIdx.x;
    {
        const float4* srcv = (const float4*)Wt;
        float4* dstv = (float4*)Wl;
        #pragma unroll
        for (int i = 0; i < 8; i++) dstv[tid + i * 256] = srcv[tid + i * 256];
    }
    int lane = tid & 63, wid = tid >> 6;
    int q = lane >> 4, j = lane & 15;
    int rowbase = blockIdx.x * 128 + wid * 32;

    float alv[8], arv[8];
    #pragma unroll
    for (int cb = 0; cb < 8; cb++) { alv[cb] = al[cb * 16 + j]; arv[cb] = ar[cb * 16 + j]; }

    short8v a[2][4];
    #pragma unroll
    for (int rb = 0; rb < 2; rb++) {
        int row = rowbase + rb * 16 + j;
        const short* ap = Abf + (size_t)row * 128 + q * 8;
        bool ok = row < nrows;
        #pragma unroll
        for (int kk = 0; kk < 4; kk++)
            a[rb][kk] = ok ? *(const short8v*)(ap + kk * 32) : (short8v)0;
    }
    __syncthreads();

    f32x4 acc[2][8] = {};
    #pragma unroll
    for (int cb = 0; cb < 8; cb++) {
        int col = cb * 16 + j;
        const short* wp = Wl + col * 128;
        int sw = (col & 7) << 3;
        #pragma unroll
        for (int kk = 0; kk < 4; kk++) {
            short8v b = *(const short8v*)(wp + ((kk * 32 + q * 8) ^ sw));
            acc[0][cb] = __builtin_amdgcn_mfma_f32_16x16x32_bf16(a[0][kk], b, acc[0][cb], 0, 0, 0);
            acc[1][cb] = __builtin_amdgcn_mfma_f32_16x16x32_bf16(a[1][kk], b, acc[1][cb], 0, 0, 0);
        }
    }

    #pragma unroll
    for (int rb = 0; rb < 2; rb++) {
        int row0 = rowbase + rb * 16 + q * 4;
        #pragma unroll
        for (int reg = 0; reg < 4; reg++) {
            int row = row0 + reg;
            if (row < nrows) {
                short* op = outB + (size_t)row * 128 + j;
                #pragma unroll
                for (int cb = 0; cb < 8; cb++) op[cb * 16] = f2bf(acc[rb][cb][reg]);
            }
        }
    }

    // fused el/er
    #pragma unroll
    for (int rb = 0; rb < 2; rb++) {
        float e0[4], e1[4], r0[4], r1[4];
        #pragma unroll
        for (int reg = 0; reg < 4; reg++) {
            float se0 = 0.f, se1 = 0.f, sr0 = 0.f, sr1 = 0.f;
            #pragma unroll
            for (int cb = 0; cb < 4; cb++) {
                se0 += acc[rb][cb][reg] * alv[cb];
                sr0 += acc[rb][cb][reg] * arv[cb];
                se1 += acc[rb][cb + 4][reg] * alv[cb + 4];
                sr1 += acc[rb][cb + 4][reg] * arv[cb + 4];
            }
            #pragma unroll
            for (int off = 1; off < 16; off <<= 1) {
                se0 += __shfl_xor(se0, off);
                se1 += __shfl_xor(se1, off);
                sr0 += __shfl_xor(sr0, off);
                sr1 += __shfl_xor(sr1, off);
            }
            e0[reg] = se0; e1[reg] = se1; r0[reg] = sr0; r1[reg] = sr1;
        }
        if (j < 4) {
            int row = rowbase + rb * 16 + q * 4 + j;
            if (row < nrows) {
                float4 v;
                v.x = j == 0 ? e0[0] : j == 1 ? e0[1] : j == 2 ? e0[2] : e0[3];
                v.y = j == 0 ? e1[0] : j == 1 ? e1[1] : j == 2 ? e1[2] : e1[3];
                v.z = j == 0 ? r0[0] : j == 1 ? r0[1] : j == 2 ? r0[2] : r0[3];
                v.w = j == 0 ? r1[0] : j == 1 ? r1[1] : j == 2 ? r1[2] : r1[3];
                elr[row] = v;
            }
        }
    }
}

// ---------------- fused softmax + gather-aggregate (wave per dst node, bf16 feat) ----------------
__global__ __launch_bounds__(256) void k_agg(const short* __restrict__ feat,
                                             const float4* __restrict__ elr,
                                             const int* __restrict__ rowptr,
                                             const int* __restrict__ csrc,
                                             const float* __restrict__ bias,
                                             float* __restrict__ acc, int nrows, int add) {
    int wid = threadIdx.x >> 6, lane = threadIdx.x & 63;
    int v = (blockIdx.x << 2) + wid;
    if (v >= nrows) return;
    int beg = rowptr[v], end = rowptr[v + 1], cnt = end - beg;
    float4 ev = elr[v];
    float m0 = -1e30f, m1 = -1e30f;
    if (cnt > 64) {   // rare path: global max first
        for (int base = beg; base < end; base += 64) {
            int idx = base + lane;
            bool val = idx < end;
            int s = val ? csrc[idx] : 0;
            float4 es = elr[s];
            float e0 = es.x + ev.z; e0 = e0 >= 0.f ? e0 : NEG_SLOPE * e0;
            float e1 = es.y + ev.w; e1 = e1 >= 0.f ? e1 : NEG_SLOPE * e1;
            if (!val) { e0 = -1e30f; e1 = -1e30f; }
            #pragma unroll
            for (int off = 32; off; off >>= 1) {
                e0 = fmaxf(e0, __shfl_xor(e0, off));
                e1 = fmaxf(e1, __shfl_xor(e1, off));
            }
            m0 = fmaxf(m0, e0); m1 = fmaxf(m1, e1);
        }
    }
    float s0 = 0.f, s1 = 0.f, a0 = 0.f, a1 = 0.f;
    for (int base = beg; base < end; base += 64) {
        int idx = base + lane;
        bool val = idx < end;
        int sv = val ? csrc[idx] : 0;
        float4 es = elr[sv];
        float e0 = es.x + ev.z; e0 = e0 >= 0.f ? e0 : NEG_SLOPE * e0;
        float e1 = es.y + ev.w; e1 = e1 >= 0.f ? e1 : NEG_SLOPE * e1;
        if (cnt <= 64) {
            float t0 = val ? e0 : -1e30f, t1 = val ? e1 : -1e30f;
            #pragma unroll
            for (int off = 32; off; off >>= 1) {
                t0 = fmaxf(t0, __shfl_xor(t0, off));
                t1 = fmaxf(t1, __shfl_xor(t1, off));
            }
            m0 = t0; m1 = t1;
        }
        float p0 = val ? __expf(e0 - m0) : 0.f;
        float p1 = val ? __expf(e1 - m1) : 0.f;
        float q0 = p0, q1 = p1;
        #pragma unroll
        for (int off = 32; off; off >>= 1) {
            q0 += __shfl_xor(q0, off);
            q1 += __shfl_xor(q1, off);
        }
        s0 += q0; s1 += q1;
        int bc = min(64, end - base);
        for (int jj = 0; jj < bc; jj++) {
            int ss = __shfl(sv, jj);
            float pp0 = __shfl(p0, jj), pp1 = __shfl(p1, jj);
            float pp = lane < 32 ? pp0 : pp1;
            unsigned u = *(const unsigned*)(feat + (size_t)ss * 128 + (lane << 1));
            a0 += pp * bflo(u);
            a1 += pp * bfhi(u);
        }
    }
    float i0 = s0 > 0.f ? 1.0f / s0 : 0.f;
    float i1 = s1 > 0.f ? 1.0f / s1 : 0.f;
    float ii = lane < 32 ? i0 : i1;
    int c0 = lane << 1;
    float r0 = a0 * ii + bias[c0];
    float r1 = a1 * ii + bias[c0 + 1];
    float2* op = (float2*)(acc + (size_t)v * 128 + c0);
    if (add) { float2 o = *op; o.x += r0; o.y += r1; *op = o; }
    else     *op = make_float2(r0, r1);
}

// ---------------- relu -> bf16 (layer-0 handoff) ----------------
__global__ void k_relu_bf(const float4* __restrict__ in, short* __restrict__ outB, int n4) {
    for (int i = blockIdx.x * blockDim.x + threadIdx.x; i < n4; i += gridDim.x * blockDim.x) {
        float4 v = in[i];
        short4v o;
        o[0] = f2bf(fmaxf(v.x, 0.f)); o[1] = f2bf(fmaxf(v.y, 0.f));
        o[2] = f2bf(fmaxf(v.z, 0.f)); o[3] = f2bf(fmaxf(v.w, 0.f));
        *(short4v*)(outB + (size_t)i * 4) = o;
    }
}

// ---------------- BN stats (fused relu) ----------------
__global__ void k_bnstat(const float* __restrict__ h, float* __restrict__ sums, int nrows) {
    int ch = threadIdx.x & 127, half = threadIdx.x >> 7;
    float s = 0.f, s2 = 0.f;
    for (int row = blockIdx.x * 2 + half; row < nrows; row += gridDim.x * 2) {
        float x = fmaxf(h[(size_t)row * 128 + ch], 0.f);
        s += x; s2 += x * x;
    }
    atomicAdd(&sums[ch], s);
    atomicAdd(&sums[128 + ch], s2);
}

// ---------------- BN-normalize + classifier GEMM (fused relu) ----------------
__global__ __launch_bounds__(256) void k_clf(const float* __restrict__ h,
                                             const float* __restrict__ sums,
                                             const float* __restrict__ bn_w,
                                             const float* __restrict__ bn_b,
                                             const float* __restrict__ Wc,
                                             const float* __restrict__ cb,
                                             float* __restrict__ out, int nrows) {
    __shared__ float Wt[64][128];
    __shared__ float2 bnp[128];
    __shared__ float hrow[4][128];
    int tid = threadIdx.x;
    for (int idx = tid; idx < 2048; idx += 256) {
        int k = idx >> 4, c4 = (idx & 15) << 2;
        float4 w = *(const float4*)(Wc + k * 64 + c4);
        int kk = k >> 2, kr = k & 3;
        Wt[c4 + 0][((kk ^ ((c4 + 0) & 7)) << 2) + kr] = w.x;
        Wt[c4 + 1][((kk ^ ((c4 + 1) & 7)) << 2) + kr] = w.y;
        Wt[c4 + 2][((kk ^ ((c4 + 2) & 7)) << 2) + kr] = w.z;
        Wt[c4 + 3][((kk ^ ((c4 + 3) & 7)) << 2) + kr] = w.w;
    }
    if (tid < 128) {
        float mu = sums[tid] / (float)nrows;
        float var = sums[128 + tid] / (float)nrows - mu * mu;
        float rs = rsqrtf(var + 1e-5f);
        float sc = bn_w[tid] * rs;
        bnp[tid] = make_float2(sc, bn_b[tid] - mu * sc);
    }
    __syncthreads();
    int wid = tid >> 6, lane = tid & 63;
    float cbv = cb[lane];
    for (int row = (blockIdx.x << 2) + wid; row < nrows; row += gridDim.x << 2) {
        float x0 = fmaxf(h[(size_t)row * 128 + lane], 0.f);
        float x1 = fmaxf(h[(size_t)row * 128 + 64 + lane], 0.f);
        hrow[wid][lane] = x0 * bnp[lane].x + bnp[lane].y;
        hrow[wid][64 + lane] = x1 * bnp[64 + lane].x + bnp[64 + lane].y;
        float acc = cbv;
        #pragma unroll
        for (int kk = 0; kk < 32; kk++) {
            float4 hv = *(float4*)&hrow[wid][kk << 2];
            float4 wv = *(float4*)&Wt[lane][(kk ^ (lane & 7)) << 2];
            acc += hv.x * wv.x + hv.y * wv.y + hv.z * wv.z + hv.w * wv.w;
        }
        out[(size_t)row * 64 + lane] = acc;
    }
}

// ---------------- launch ----------------

extern "C" void kernel_launch(void* const* d_in, const int* in_sizes, int n_in,
                              void* d_out, int out_size, void* d_ws, size_t ws_size,
                              hipStream_t stream) {
    (void)in_sizes; (void)n_in; (void)out_size; (void)ws_size;
    const float* feat_in = (const float*)d_in[0];
    const float* Ws      = (const float*)d_in[1];
    const float* als     = (const float*)d_in[2];
    const float* ars     = (const float*)d_in[3];
    const float* bs      = (const float*)d_in[4];
    const float* bn_w    = (const float*)d_in[5];
    const float* bn_b    = (const float*)d_in[6];
    const float* clf_W   = (const float*)d_in[7];
    const float* clf_b   = (const float*)d_in[8];
    const int*   src     = (const int*)d_in[9];
    const int*   dst     = (const int*)d_in[10];
    float* out = (float*)d_out;

    const int N = N_NODES, E = N_EDGES;
    char* p = (char*)d_ws;
    auto carve = [&](size_t bytes) { char* q = p; p += (bytes + 255) & ~255ULL; return q; };
    int*    bcnt   = (int*)carve((size_t)3 * NB * 4);
    int*    bptr   = (int*)carve((size_t)3 * (NB + 1) * 4);
    int*    bcur   = (int*)carve((size_t)3 * NB * 4);
    int*    rowptr = (int*)carve((size_t)3 * (N + 1) * 4);
    int*    csrc   = (int*)carve((size_t)3 * E * 4);
    uint2*  ebin   = (uint2*)carve((size_t)3 * E * 8);
    float4* elr    = (float4*)carve((size_t)N * 16);
    float*  bnsum  = (float*)carve(256 * 4);
    short*  Wtg    = (short*)carve((size_t)6 * 16384 * 2);
    short*  hbf    = (short*)carve((size_t)N * 128 * 2);
    short*  featb  = (short*)carve((size_t)N * 128 * 2);
    float*  accb   = (float*)carve((size_t)N * 128 * 4);

    // weight prep + input conversion
    k_wprep<<<(6 * 16384 + 255) / 256, 256, 0, stream>>>(Ws, Wtg);
    k_cvt<<<2048, 256, 0, stream>>>(feat_in, hbf, N * 128);

    // CSR build via binned sort
    hipMemsetAsync(bcnt, 0, (size_t)3 * NB * 4, stream);
    dim3 gchunk((E + 4095) / 4096, 3);
    k_bhist<<<gchunk, 256, 0, stream>>>(dst, bcnt);
    k_bscan<<<3, 64, 0, stream>>>(bcnt, bptr, bcur);
    k_bin<<<gchunk, 256, 0, stream>>>(src, dst, bcur, ebin);
    dim3 gbkt(NB, 3);
    k_nhist<<<gbkt, 256, 0, stream>>>(ebin, bptr, rowptr);
    k_scat2<<<gbkt, 256, 0, stream>>>(ebin, bptr, rowptr, csrc);

    for (int l = 0; l < 2; l++) {
        for (int r = 0; r < 3; r++) {
            int lr = l * 3 + r;
            k_gemm<<<(N + 127) / 128, 256, 0, stream>>>(hbf, Wtg + (size_t)lr * 16384,
                                                        als + lr * 128, ars + lr * 128,
                                                        featb, elr, N);
            k_agg<<<(N + 3) / 4, 256, 0, stream>>>(featb, elr, rowptr + r * (N + 1),
                                                   csrc + (size_t)r * E, bs + lr * 128,
                                                   accb, N, r);
        }
        if (l == 0)
            k_relu_bf<<<2048, 256, 0, stream>>>((const float4*)accb, hbf, N * 32);
        // l == 1: relu fused into k_bnstat / k_clf
    }

    hipMemsetAsync(bnsum, 0, 256 * 4, stream);
    k_bnstat<<<2048, 256, 0, stream>>>(accb, bnsum, N);
    k_clf<<<1024, 256, 0, stream>>>(accb, bnsum, bn_w, bn_b, clf_W, clf_b, out, N);
}

// Round 5
// 668.156 us; speedup vs baseline: 3.2515x; 1.1428x over previous
//
#include <hip/hip_runtime.h>
#include <hip/hip_bf16.h>

#define N_NODES 100000
#define N_EDGES 500000
#define HID 128
#define NEG_SLOPE 0.2f
#define NB 98           // buckets of 1024 nodes: ceil(100000/1024)

typedef __attribute__((ext_vector_type(8))) short short8v;
typedef __attribute__((ext_vector_type(4))) short short4v;
typedef __attribute__((ext_vector_type(4))) float f32x4;

__device__ __forceinline__ short f2bf(float x) {
    union { float f; unsigned u; } v; v.f = x;
    unsigned r = v.u + 0x7fff + ((v.u >> 16) & 1);  // RNE
    return (short)(r >> 16);
}
__device__ __forceinline__ float bflo(unsigned u) {
    union { unsigned x; float f; } c; c.x = u << 16; return c.f;
}
__device__ __forceinline__ float bfhi(unsigned u) {
    union { unsigned x; float f; } c; c.x = u & 0xffff0000u; return c.f;
}

// ---------------- CSR build: binned two-level sort ----------------

__global__ __launch_bounds__(256) void k_bhist(const int* __restrict__ dst, int* __restrict__ bcnt) {
    int r = blockIdx.y, tid = threadIdx.x;
    int base = blockIdx.x * 4096;
    __shared__ int h[128];
    if (tid < 128) h[tid] = 0;
    __syncthreads();
    size_t eb = (size_t)r * N_EDGES;
    int lim = min(base + 4096, N_EDGES);
    for (int e = base + tid; e < lim; e += 256) atomicAdd(&h[dst[eb + e] >> 10], 1);
    __syncthreads();
    if (tid < NB && h[tid]) atomicAdd(&bcnt[r * NB + tid], h[tid]);
}

__global__ void k_bscan(const int* __restrict__ bcnt, int* __restrict__ bptr, int* __restrict__ bcur) {
    int r = blockIdx.x, lane = threadIdx.x;
    int carry = 0;
    for (int base = 0; base < NB; base += 64) {
        int i = base + lane;
        int c = (i < NB) ? bcnt[r * NB + i] : 0;
        int v = c;
        #pragma unroll
        for (int d = 1; d < 64; d <<= 1) { int t = __shfl_up(v, d); if (lane >= d) v += t; }
        int excl = carry + v - c;
        if (i < NB) { bptr[r * (NB + 1) + i] = excl; bcur[r * NB + i] = excl; }
        carry += __shfl(v, 63);
    }
    if (lane == 0) bptr[r * (NB + 1) + NB] = carry;
}

// bin edges into bucket regions of ebin packed as ((dst&1023)<<17 | src)
__global__ __launch_bounds__(256) void k_bin(const int* __restrict__ src, const int* __restrict__ dst,
                                             int* __restrict__ bcur, unsigned* __restrict__ ebin) {
    int r = blockIdx.y, tid = threadIdx.x;
    int base = blockIdx.x * 4096;
    __shared__ int cnt[128], incl[128], gb[128], wcur[128];
    __shared__ uint2 stage[4096];
    if (tid < 128) cnt[tid] = 0;
    __syncthreads();
    int myd[16], mys[16];
    size_t eb = (size_t)r * N_EDGES;
    #pragma unroll
    for (int i = 0; i < 16; i++) {
        int e = base + i * 256 + tid;
        if (e < N_EDGES) {
            int d = dst[eb + e];
            myd[i] = d; mys[i] = src[eb + e];
            atomicAdd(&cnt[d >> 10], 1);
        } else myd[i] = -1;
    }
    __syncthreads();
    if (tid < 128) incl[tid] = cnt[tid];
    __syncthreads();
    for (int d = 1; d < 128; d <<= 1) {
        int t = 0;
        if (tid < 128 && tid >= d) t = incl[tid - d];
        __syncthreads();
        if (tid < 128 && tid >= d) incl[tid] += t;
        __syncthreads();
    }
    if (tid < 128) {
        wcur[tid] = incl[tid] - cnt[tid];
        gb[tid] = (tid < NB && cnt[tid] > 0) ? atomicAdd(&bcur[r * NB + tid], cnt[tid]) : 0;
    }
    __syncthreads();
    #pragma unroll
    for (int i = 0; i < 16; i++) {
        if (myd[i] >= 0) {
            int bkt = myd[i] >> 10;
            int p = atomicAdd(&wcur[bkt], 1);
            stage[p] = make_uint2((unsigned)myd[i], (unsigned)mys[i]);
        }
    }
    __syncthreads();
    int tot = min(4096, N_EDGES - base);
    for (int i = tid; i < tot; i += 256) {
        uint2 u = stage[i];
        int bkt = (int)(u.x >> 10);
        int ex = incl[bkt] - cnt[bkt];
        ebin[eb + gb[bkt] + (i - ex)] = ((u.x & 1023u) << 17) | u.y;
    }
}

__global__ __launch_bounds__(256) void k_nhist(const unsigned* __restrict__ ebin,
                                               const int* __restrict__ bptr,
                                               int* __restrict__ rowptr) {
    int b = blockIdx.x, r = blockIdx.y, tid = threadIdx.x;
    __shared__ int cnt[1024];
    __shared__ int wsum[4];
    for (int i = tid; i < 1024; i += 256) cnt[i] = 0;
    __syncthreads();
    int es = bptr[r * (NB + 1) + b], ee = bptr[r * (NB + 1) + b + 1];
    size_t eb = (size_t)r * N_EDGES;
    for (int i = es + tid; i < ee; i += 256) atomicAdd(&cnt[(ebin[eb + i] >> 17) & 1023u], 1);
    __syncthreads();
    int b4 = tid * 4;
    int c0 = cnt[b4], c1 = cnt[b4 + 1], c2 = cnt[b4 + 2], c3 = cnt[b4 + 3];
    int ts = c0 + c1 + c2 + c3;
    int lane = tid & 63, wid = tid >> 6;
    int v = ts;
    #pragma unroll
    for (int d = 1; d < 64; d <<= 1) { int t = __shfl_up(v, d); if (lane >= d) v += t; }
    if (lane == 63) wsum[wid] = v;
    __syncthreads();
    int woff = 0;
    for (int w = 0; w < wid; w++) woff += wsum[w];
    int p = woff + v - ts;
    int node0 = b << 10;
    int rp = r * (N_NODES + 1);
    int nd;
    nd = node0 + b4;     if (nd < N_NODES) rowptr[rp + nd] = es + p; p += c0;
    nd = node0 + b4 + 1; if (nd < N_NODES) rowptr[rp + nd] = es + p; p += c1;
    nd = node0 + b4 + 2; if (nd < N_NODES) rowptr[rp + nd] = es + p; p += c2;
    nd = node0 + b4 + 3; if (nd < N_NODES) rowptr[rp + nd] = es + p;
    if (b == NB - 1 && tid == 0) rowptr[rp + N_NODES] = bptr[r * (NB + 1) + NB];
}

__global__ __launch_bounds__(256) void k_scat2(const unsigned* __restrict__ ebin,
                                               const int* __restrict__ bptr,
                                               const int* __restrict__ rowptr,
                                               int* __restrict__ csrc) {
    int b = blockIdx.x, r = blockIdx.y, tid = threadIdx.x;
    __shared__ int cnt[1024];
    __shared__ int rloc[1024];
    __shared__ int stage[8192];
    int node0 = b << 10;
    int rp = r * (N_NODES + 1);
    int rs = rowptr[rp + node0];
    for (int i = tid; i < 1024; i += 256) {
        cnt[i] = 0;
        int nd = node0 + i; if (nd > N_NODES) nd = N_NODES;
        rloc[i] = rowptr[rp + nd] - rs;
    }
    __syncthreads();
    int es = bptr[r * (NB + 1) + b], ee = bptr[r * (NB + 1) + b + 1];
    int sz = ee - es;
    size_t eb = (size_t)r * N_EDGES;
    if (sz <= 8192) {
        for (int i = es + tid; i < ee; i += 256) {
            unsigned u = ebin[eb + i];
            int dl = (int)((u >> 17) & 1023u);
            int rk = atomicAdd(&cnt[dl], 1);
            stage[rloc[dl] + rk] = (int)(u & 0x1FFFFu);
        }
        __syncthreads();
        for (int i = tid; i < sz; i += 256) csrc[eb + rs + i] = stage[i];
    } else {
        for (int i = es + tid; i < ee; i += 256) {
            unsigned u = ebin[eb + i];
            int dl = (int)((u >> 17) & 1023u);
            int rk = atomicAdd(&cnt[dl], 1);
            csrc[eb + rs + rloc[dl] + rk] = (int)(u & 0x1FFFFu);
        }
    }
}

// ---------------- W prep ----------------
__global__ void k_wprep(const float* __restrict__ Ws, short* __restrict__ Wt) {
    int i = blockIdx.x * blockDim.x + threadIdx.x;
    if (i < 6 * 16384) {
        int lr = i >> 14, rem = i & 16383, k = rem >> 7, col = rem & 127;
        Wt[lr * 16384 + col * 128 + (k ^ ((col & 7) << 3))] = f2bf(Ws[i]);
    }
}

// ---------------- f32 -> bf16 bulk convert ----------------
__global__ void k_cvt(const float* __restrict__ in, short* __restrict__ out, int n) {
    int i = blockIdx.x * blockDim.x + threadIdx.x;
    int stride = gridDim.x * blockDim.x;
    for (int base = i * 8; base < n; base += stride * 8) {
        float4 x = *(const float4*)(in + base);
        float4 y = *(const float4*)(in + base + 4);
        short8v o;
        o[0] = f2bf(x.x); o[1] = f2bf(x.y); o[2] = f2bf(x.z); o[3] = f2bf(x.w);
        o[4] = f2bf(y.x); o[5] = f2bf(y.y); o[6] = f2bf(y.z); o[7] = f2bf(y.w);
        *(short8v*)(out + base) = o;
    }
}

// ---------------- MFMA GEMM: bf16 out + fused el/er ----------------
__global__ __launch_bounds__(256) void k_gemm(const short* __restrict__ Abf,
                                              const short* __restrict__ Wt,
                                              const float* __restrict__ al,
                                              const float* __restrict__ ar,
                                              short* __restrict__ outB,
                                              float4* __restrict__ elr, int nrows) {
    __shared__ __align__(16) short Wl[128 * 128];
    int tid = threadIdx.x;
    {
        const float4* srcv = (const float4*)Wt;
        float4* dstv = (float4*)Wl;
        #pragma unroll
        for (int i = 0; i < 8; i++) dstv[tid + i * 256] = srcv[tid + i * 256];
    }
    int lane = tid & 63, wid = tid >> 6;
    int q = lane >> 4, j = lane & 15;
    int rowbase = blockIdx.x * 128 + wid * 32;

    float alv[8], arv[8];
    #pragma unroll
    for (int cb = 0; cb < 8; cb++) { alv[cb] = al[cb * 16 + j]; arv[cb] = ar[cb * 16 + j]; }

    short8v a[2][4];
    #pragma unroll
    for (int rb = 0; rb < 2; rb++) {
        int row = rowbase + rb * 16 + j;
        const short* ap = Abf + (size_t)row * 128 + q * 8;
        bool ok = row < nrows;
        #pragma unroll
        for (int kk = 0; kk < 4; kk++)
            a[rb][kk] = ok ? *(const short8v*)(ap + kk * 32) : (short8v)0;
    }
    __syncthreads();

    f32x4 acc[2][8] = {};
    #pragma unroll
    for (int cb = 0; cb < 8; cb++) {
        int col = cb * 16 + j;
        const short* wp = Wl + col * 128;
        int sw = (col & 7) << 3;
        #pragma unroll
        for (int kk = 0; kk < 4; kk++) {
            short8v b = *(const short8v*)(wp + ((kk * 32 + q * 8) ^ sw));
            acc[0][cb] = __builtin_amdgcn_mfma_f32_16x16x32_bf16(a[0][kk], b, acc[0][cb], 0, 0, 0);
            acc[1][cb] = __builtin_amdgcn_mfma_f32_16x16x32_bf16(a[1][kk], b, acc[1][cb], 0, 0, 0);
        }
    }

    #pragma unroll
    for (int rb = 0; rb < 2; rb++) {
        int row0 = rowbase + rb * 16 + q * 4;
        #pragma unroll
        for (int reg = 0; reg < 4; reg++) {
            int row = row0 + reg;
            if (row < nrows) {
                short* op = outB + (size_t)row * 128 + j;
                #pragma unroll
                for (int cb = 0; cb < 8; cb++) op[cb * 16] = f2bf(acc[rb][cb][reg]);
            }
        }
    }

    // fused el/er
    #pragma unroll
    for (int rb = 0; rb < 2; rb++) {
        float e0[4], e1[4], r0[4], r1[4];
        #pragma unroll
        for (int reg = 0; reg < 4; reg++) {
            float se0 = 0.f, se1 = 0.f, sr0 = 0.f, sr1 = 0.f;
            #pragma unroll
            for (int cb = 0; cb < 4; cb++) {
                se0 += acc[rb][cb][reg] * alv[cb];
                sr0 += acc[rb][cb][reg] * arv[cb];
                se1 += acc[rb][cb + 4][reg] * alv[cb + 4];
                sr1 += acc[rb][cb + 4][reg] * arv[cb + 4];
            }
            #pragma unroll
            for (int off = 1; off < 16; off <<= 1) {
                se0 += __shfl_xor(se0, off);
                se1 += __shfl_xor(se1, off);
                sr0 += __shfl_xor(sr0, off);
                sr1 += __shfl_xor(sr1, off);
            }
            e0[reg] = se0; e1[reg] = se1; r0[reg] = sr0; r1[reg] = sr1;
        }
        if (j < 4) {
            int row = rowbase + rb * 16 + q * 4 + j;
            if (row < nrows) {
                float4 v;
                v.x = j == 0 ? e0[0] : j == 1 ? e0[1] : j == 2 ? e0[2] : e0[3];
                v.y = j == 0 ? e1[0] : j == 1 ? e1[1] : j == 2 ? e1[2] : e1[3];
                v.z = j == 0 ? r0[0] : j == 1 ? r0[1] : j == 2 ? r0[2] : r0[3];
                v.w = j == 0 ? r1[0] : j == 1 ? r1[1] : j == 2 ? r1[2] : r1[3];
                elr[row] = v;
            }
        }
    }
}

// ---------------- fused softmax + gather-aggregate ----------------
// mode: 0 = store accb; 1 = accumulate accb; 2 = accumulate + relu -> bf16 hbf (skip accb write)
__global__ __launch_bounds__(256) void k_agg(const short* __restrict__ feat,
                                             const float4* __restrict__ elr,
                                             const int* __restrict__ rowptr,
                                             const int* __restrict__ csrc,
                                             const float* __restrict__ bias,
                                             float* __restrict__ acc,
                                             short* __restrict__ hb, int nrows, int mode) {
    int wid = threadIdx.x >> 6, lane = threadIdx.x & 63;
    int v = (blockIdx.x << 2) + wid;
    if (v >= nrows) return;
    int beg = rowptr[v], end = rowptr[v + 1], cnt = end - beg;
    float4 ev = elr[v];
    float m0 = -1e30f, m1 = -1e30f;
    if (cnt > 64) {
        for (int base = beg; base < end; base += 64) {
            int idx = base + lane;
            bool val = idx < end;
            int s = val ? csrc[idx] : 0;
            float4 es = elr[s];
            float e0 = es.x + ev.z; e0 = e0 >= 0.f ? e0 : NEG_SLOPE * e0;
            float e1 = es.y + ev.w; e1 = e1 >= 0.f ? e1 : NEG_SLOPE * e1;
            if (!val) { e0 = -1e30f; e1 = -1e30f; }
            #pragma unroll
            for (int off = 32; off; off >>= 1) {
                e0 = fmaxf(e0, __shfl_xor(e0, off));
                e1 = fmaxf(e1, __shfl_xor(e1, off));
            }
            m0 = fmaxf(m0, e0); m1 = fmaxf(m1, e1);
        }
    }
    float s0 = 0.f, s1 = 0.f, a0 = 0.f, a1 = 0.f;
    for (int base = beg; base < end; base += 64) {
        int idx = base + lane;
        bool val = idx < end;
        int sv = val ? csrc[idx] : 0;
        float4 es = elr[sv];
        float e0 = es.x + ev.z; e0 = e0 >= 0.f ? e0 : NEG_SLOPE * e0;
        float e1 = es.y + ev.w; e1 = e1 >= 0.f ? e1 : NEG_SLOPE * e1;
        if (cnt <= 64) {
            float t0 = val ? e0 : -1e30f, t1 = val ? e1 : -1e30f;
            #pragma unroll
            for (int off = 32; off; off >>= 1) {
                t0 = fmaxf(t0, __shfl_xor(t0, off));
                t1 = fmaxf(t1, __shfl_xor(t1, off));
            }
            m0 = t0; m1 = t1;
        }
        float p0 = val ? __expf(e0 - m0) : 0.f;
        float p1 = val ? __expf(e1 - m1) : 0.f;
        float q0 = p0, q1 = p1;
        #pragma unroll
        for (int off = 32; off; off >>= 1) {
            q0 += __shfl_xor(q0, off);
            q1 += __shfl_xor(q1, off);
        }
        s0 += q0; s1 += q1;
        int bc = min(64, end - base);
        for (int jj = 0; jj < bc; jj++) {
            int ss = __shfl(sv, jj);
            float pp0 = __shfl(p0, jj), pp1 = __shfl(p1, jj);
            float pp = lane < 32 ? pp0 : pp1;
            unsigned u = *(const unsigned*)(feat + (size_t)ss * 128 + (lane << 1));
            a0 += pp * bflo(u);
            a1 += pp * bfhi(u);
        }
    }
    float i0 = s0 > 0.f ? 1.0f / s0 : 0.f;
    float i1 = s1 > 0.f ? 1.0f / s1 : 0.f;
    float ii = lane < 32 ? i0 : i1;
    int c0 = lane << 1;
    float r0 = a0 * ii + bias[c0];
    float r1 = a1 * ii + bias[c0 + 1];
    float2* op = (float2*)(acc + (size_t)v * 128 + c0);
    if (mode == 0) {
        *op = make_float2(r0, r1);
    } else {
        float2 o = *op; r0 += o.x; r1 += o.y;
        if (mode == 1) {
            *op = make_float2(r0, r1);
        } else {  // mode 2: relu -> bf16 into hb, no accb write
            unsigned pk = ((unsigned)(unsigned short)f2bf(fmaxf(r0, 0.f))) |
                          (((unsigned)(unsigned short)f2bf(fmaxf(r1, 0.f))) << 16);
            *(unsigned*)(hb + (size_t)v * 128 + c0) = pk;
        }
    }
}

// ---------------- BN stats (fused relu, vectorized) ----------------
__global__ __launch_bounds__(256) void k_bnstat(const float4* __restrict__ h,
                                                float* __restrict__ sums, int nrows) {
    int tid = threadIdx.x;
    int c4 = tid & 31, rgrp = tid >> 5;
    float4 s = make_float4(0.f, 0.f, 0.f, 0.f), q = make_float4(0.f, 0.f, 0.f, 0.f);
    for (int row = blockIdx.x * 8 + rgrp; row < nrows; row += gridDim.x * 8) {
        float4 v = h[(size_t)row * 32 + c4];
        v.x = fmaxf(v.x, 0.f); v.y = fmaxf(v.y, 0.f);
        v.z = fmaxf(v.z, 0.f); v.w = fmaxf(v.w, 0.f);
        s.x += v.x; s.y += v.y; s.z += v.z; s.w += v.w;
        q.x += v.x * v.x; q.y += v.y * v.y; q.z += v.z * v.z; q.w += v.w * v.w;
    }
    __shared__ float ls[8][128], lq[8][128];
    *(float4*)&ls[rgrp][c4 * 4] = s;
    *(float4*)&lq[rgrp][c4 * 4] = q;
    __syncthreads();
    if (tid < 128) {
        float ts = 0.f, tq = 0.f;
        #pragma unroll
        for (int g = 0; g < 8; g++) { ts += ls[g][tid]; tq += lq[g][tid]; }
        atomicAdd(&sums[tid], ts);
        atomicAdd(&sums[128 + tid], tq);
    }
}

// ---------------- BN-normalize + classifier GEMM (fused relu) ----------------
__global__ __launch_bounds__(256) void k_clf(const float* __restrict__ h,
                                             const float* __restrict__ sums,
                                             const float* __restrict__ bn_w,
                                             const float* __restrict__ bn_b,
                                             const float* __restrict__ Wc,
                                             const float* __restrict__ cb,
                                             float* __restrict__ out, int nrows) {
    __shared__ float Wt[64][128];
    __shared__ float2 bnp[128];
    __shared__ float hrow[4][128];
    int tid = threadIdx.x;
    for (int idx = tid; idx < 2048; idx += 256) {
        int k = idx >> 4, c4 = (idx & 15) << 2;
        float4 w = *(const float4*)(Wc + k * 64 + c4);
        int kk = k >> 2, kr = k & 3;
        Wt[c4 + 0][((kk ^ ((c4 + 0) & 7)) << 2) + kr] = w.x;
        Wt[c4 + 1][((kk ^ ((c4 + 1) & 7)) << 2) + kr] = w.y;
        Wt[c4 + 2][((kk ^ ((c4 + 2) & 7)) << 2) + kr] = w.z;
        Wt[c4 + 3][((kk ^ ((c4 + 3) & 7)) << 2) + kr] = w.w;
    }
    if (tid < 128) {
        float mu = sums[tid] / (float)nrows;
        float var = sums[128 + tid] / (float)nrows - mu * mu;
        float rs = rsqrtf(var + 1e-5f);
        float sc = bn_w[tid] * rs;
        bnp[tid] = make_float2(sc, bn_b[tid] - mu * sc);
    }
    __syncthreads();
    int wid = tid >> 6, lane = tid & 63;
    float cbv = cb[lane];
    for (int row = (blockIdx.x << 2) + wid; row < nrows; row += gridDim.x << 2) {
        float x0 = fmaxf(h[(size_t)row * 128 + lane], 0.f);
        float x1 = fmaxf(h[(size_t)row * 128 + 64 + lane], 0.f);
        hrow[wid][lane] = x0 * bnp[lane].x + bnp[lane].y;
        hrow[wid][64 + lane] = x1 * bnp[64 + lane].x + bnp[64 + lane].y;
        float acc = cbv;
        #pragma unroll
        for (int kk = 0; kk < 32; kk++) {
            float4 hv = *(float4*)&hrow[wid][kk << 2];
            float4 wv = *(float4*)&Wt[lane][(kk ^ (lane & 7)) << 2];
            acc += hv.x * wv.x + hv.y * wv.y + hv.z * wv.z + hv.w * wv.w;
        }
        out[(size_t)row * 64 + lane] = acc;
    }
}

// ---------------- launch ----------------

extern "C" void kernel_launch(void* const* d_in, const int* in_sizes, int n_in,
                              void* d_out, int out_size, void* d_ws, size_t ws_size,
                              hipStream_t stream) {
    (void)in_sizes; (void)n_in; (void)out_size; (void)ws_size;
    const float* feat_in = (const float*)d_in[0];
    const float* Ws      = (const float*)d_in[1];
    const float* als     = (const float*)d_in[2];
    const float* ars     = (const float*)d_in[3];
    const float* bs      = (const float*)d_in[4];
    const float* bn_w    = (const float*)d_in[5];
    const float* bn_b    = (const float*)d_in[6];
    const float* clf_W   = (const float*)d_in[7];
    const float* clf_b   = (const float*)d_in[8];
    const int*   src     = (const int*)d_in[9];
    const int*   dst     = (const int*)d_in[10];
    float* out = (float*)d_out;

    const int N = N_NODES, E = N_EDGES;
    char* p = (char*)d_ws;
    auto carve = [&](size_t bytes) { char* q = p; p += (bytes + 255) & ~255ULL; return q; };
    int*      bcnt   = (int*)carve((size_t)3 * NB * 4);
    int*      bptr   = (int*)carve((size_t)3 * (NB + 1) * 4);
    int*      bcur   = (int*)carve((size_t)3 * NB * 4);
    int*      rowptr = (int*)carve((size_t)3 * (N + 1) * 4);
    int*      csrc   = (int*)carve((size_t)3 * E * 4);
    unsigned* ebin   = (unsigned*)carve((size_t)3 * E * 4);
    float4*   elr    = (float4*)carve((size_t)N * 16);
    float*    bnsum  = (float*)carve(256 * 4);
    short*    Wtg    = (short*)carve((size_t)6 * 16384 * 2);
    short*    hbf    = (short*)carve((size_t)N * 128 * 2);
    short*    featb  = (short*)carve((size_t)N * 128 * 2);
    float*    accb   = (float*)carve((size_t)N * 128 * 4);

    // weight prep + input conversion
    k_wprep<<<(6 * 16384 + 255) / 256, 256, 0, stream>>>(Ws, Wtg);
    k_cvt<<<2048, 256, 0, stream>>>(feat_in, hbf, N * 128);

    // CSR build via binned sort
    hipMemsetAsync(bcnt, 0, (size_t)3 * NB * 4, stream);
    dim3 gchunk((E + 4095) / 4096, 3);
    k_bhist<<<gchunk, 256, 0, stream>>>(dst, bcnt);
    k_bscan<<<3, 64, 0, stream>>>(bcnt, bptr, bcur);
    k_bin<<<gchunk, 256, 0, stream>>>(src, dst, bcur, ebin);
    dim3 gbkt(NB, 3);
    k_nhist<<<gbkt, 256, 0, stream>>>(ebin, bptr, rowptr);
    k_scat2<<<gbkt, 256, 0, stream>>>(ebin, bptr, rowptr, csrc);

    for (int l = 0; l < 2; l++) {
        for (int r = 0; r < 3; r++) {
            int lr = l * 3 + r;
            int mode = (r == 0) ? 0 : ((r == 2 && l == 0) ? 2 : 1);
            k_gemm<<<(N + 127) / 128, 256, 0, stream>>>(hbf, Wtg + (size_t)lr * 16384,
                                                        als + lr * 128, ars + lr * 128,
                                                        featb, elr, N);
            k_agg<<<(N + 3) / 4, 256, 0, stream>>>(featb, elr, rowptr + r * (N + 1),
                                                   csrc + (size_t)r * E, bs + lr * 128,
                                                   accb, hbf, N, mode);
        }
    }

    hipMemsetAsync(bnsum, 0, 256 * 4, stream);
    k_bnstat<<<512, 256, 0, stream>>>((const float4*)accb, bnsum, N);
    k_clf<<<1024, 256, 0, stream>>>(accb, bnsum, bn_w, bn_b, clf_W, clf_b, out, N);
}

// Round 6
// 602.737 us; speedup vs baseline: 3.6044x; 1.1085x over previous
//
#include <hip/hip_runtime.h>
#include <hip/hip_bf16.h>

#define N_NODES 100000
#define N_EDGES 500000
#define HID 128
#define NEG_SLOPE 0.2f
#define NB 98           // buckets of 1024 nodes: ceil(100000/1024)

typedef __attribute__((ext_vector_type(8))) short short8v;
typedef __attribute__((ext_vector_type(4))) short short4v;
typedef __attribute__((ext_vector_type(4))) float f32x4;

__device__ __forceinline__ short f2bf(float x) {
    union { float f; unsigned u; } v; v.f = x;
    unsigned r = v.u + 0x7fff + ((v.u >> 16) & 1);  // RNE
    return (short)(r >> 16);
}
__device__ __forceinline__ float bflo(unsigned u) {
    union { unsigned x; float f; } c; c.x = u << 16; return c.f;
}
__device__ __forceinline__ float bfhi(unsigned u) {
    union { unsigned x; float f; } c; c.x = u & 0xffff0000u; return c.f;
}

// ---------------- CSR build: binned two-level sort ----------------

__global__ __launch_bounds__(256) void k_bhist(const int* __restrict__ dst, int* __restrict__ bcnt) {
    int r = blockIdx.y, tid = threadIdx.x;
    int base = blockIdx.x * 4096;
    __shared__ int h[128];
    if (tid < 128) h[tid] = 0;
    __syncthreads();
    size_t eb = (size_t)r * N_EDGES;
    int lim = min(base + 4096, N_EDGES);
    for (int e = base + tid; e < lim; e += 256) atomicAdd(&h[dst[eb + e] >> 10], 1);
    __syncthreads();
    if (tid < NB && h[tid]) atomicAdd(&bcnt[r * NB + tid], h[tid]);
}

__global__ void k_bscan(const int* __restrict__ bcnt, int* __restrict__ bptr, int* __restrict__ bcur) {
    int r = blockIdx.x, lane = threadIdx.x;
    int carry = 0;
    for (int base = 0; base < NB; base += 64) {
        int i = base + lane;
        int c = (i < NB) ? bcnt[r * NB + i] : 0;
        int v = c;
        #pragma unroll
        for (int d = 1; d < 64; d <<= 1) { int t = __shfl_up(v, d); if (lane >= d) v += t; }
        int excl = carry + v - c;
        if (i < NB) { bptr[r * (NB + 1) + i] = excl; bcur[r * NB + i] = excl; }
        carry += __shfl(v, 63);
    }
    if (lane == 0) bptr[r * (NB + 1) + NB] = carry;
}

// bin edges into bucket regions of ebin packed as ((dst&1023)<<17 | src)
__global__ __launch_bounds__(256) void k_bin(const int* __restrict__ src, const int* __restrict__ dst,
                                             int* __restrict__ bcur, unsigned* __restrict__ ebin) {
    int r = blockIdx.y, tid = threadIdx.x;
    int base = blockIdx.x * 4096;
    __shared__ int cnt[128], incl[128], gb[128], wcur[128];
    __shared__ uint2 stage[4096];
    if (tid < 128) cnt[tid] = 0;
    __syncthreads();
    int myd[16], mys[16];
    size_t eb = (size_t)r * N_EDGES;
    #pragma unroll
    for (int i = 0; i < 16; i++) {
        int e = base + i * 256 + tid;
        if (e < N_EDGES) {
            int d = dst[eb + e];
            myd[i] = d; mys[i] = src[eb + e];
            atomicAdd(&cnt[d >> 10], 1);
        } else myd[i] = -1;
    }
    __syncthreads();
    if (tid < 128) incl[tid] = cnt[tid];
    __syncthreads();
    for (int d = 1; d < 128; d <<= 1) {
        int t = 0;
        if (tid < 128 && tid >= d) t = incl[tid - d];
        __syncthreads();
        if (tid < 128 && tid >= d) incl[tid] += t;
        __syncthreads();
    }
    if (tid < 128) {
        wcur[tid] = incl[tid] - cnt[tid];
        gb[tid] = (tid < NB && cnt[tid] > 0) ? atomicAdd(&bcur[r * NB + tid], cnt[tid]) : 0;
    }
    __syncthreads();
    #pragma unroll
    for (int i = 0; i < 16; i++) {
        if (myd[i] >= 0) {
            int bkt = myd[i] >> 10;
            int p = atomicAdd(&wcur[bkt], 1);
            stage[p] = make_uint2((unsigned)myd[i], (unsigned)mys[i]);
        }
    }
    __syncthreads();
    int tot = min(4096, N_EDGES - base);
    for (int i = tid; i < tot; i += 256) {
        uint2 u = stage[i];
        int bkt = (int)(u.x >> 10);
        int ex = incl[bkt] - cnt[bkt];
        ebin[eb + gb[bkt] + (i - ex)] = ((u.x & 1023u) << 17) | u.y;
    }
}

__global__ __launch_bounds__(256) void k_nhist(const unsigned* __restrict__ ebin,
                                               const int* __restrict__ bptr,
                                               int* __restrict__ rowptr) {
    int b = blockIdx.x, r = blockIdx.y, tid = threadIdx.x;
    __shared__ int cnt[1024];
    __shared__ int wsum[4];
    for (int i = tid; i < 1024; i += 256) cnt[i] = 0;
    __syncthreads();
    int es = bptr[r * (NB + 1) + b], ee = bptr[r * (NB + 1) + b + 1];
    size_t eb = (size_t)r * N_EDGES;
    for (int i = es + tid; i < ee; i += 256) atomicAdd(&cnt[(ebin[eb + i] >> 17) & 1023u], 1);
    __syncthreads();
    int b4 = tid * 4;
    int c0 = cnt[b4], c1 = cnt[b4 + 1], c2 = cnt[b4 + 2], c3 = cnt[b4 + 3];
    int ts = c0 + c1 + c2 + c3;
    int lane = tid & 63, wid = tid >> 6;
    int v = ts;
    #pragma unroll
    for (int d = 1; d < 64; d <<= 1) { int t = __shfl_up(v, d); if (lane >= d) v += t; }
    if (lane == 63) wsum[wid] = v;
    __syncthreads();
    int woff = 0;
    for (int w = 0; w < wid; w++) woff += wsum[w];
    int p = woff + v - ts;
    int node0 = b << 10;
    int rp = r * (N_NODES + 1);
    int nd;
    nd = node0 + b4;     if (nd < N_NODES) rowptr[rp + nd] = es + p; p += c0;
    nd = node0 + b4 + 1; if (nd < N_NODES) rowptr[rp + nd] = es + p; p += c1;
    nd = node0 + b4 + 2; if (nd < N_NODES) rowptr[rp + nd] = es + p; p += c2;
    nd = node0 + b4 + 3; if (nd < N_NODES) rowptr[rp + nd] = es + p;
    if (b == NB - 1 && tid == 0) rowptr[rp + N_NODES] = bptr[r * (NB + 1) + NB];
}

__global__ __launch_bounds__(256) void k_scat2(const unsigned* __restrict__ ebin,
                                               const int* __restrict__ bptr,
                                               const int* __restrict__ rowptr,
                                               int* __restrict__ csrc) {
    int b = blockIdx.x, r = blockIdx.y, tid = threadIdx.x;
    __shared__ int cnt[1024];
    __shared__ int rloc[1024];
    __shared__ int stage[8192];
    int node0 = b << 10;
    int rp = r * (N_NODES + 1);
    int rs = rowptr[rp + node0];
    for (int i = tid; i < 1024; i += 256) {
        cnt[i] = 0;
        int nd = node0 + i; if (nd > N_NODES) nd = N_NODES;
        rloc[i] = rowptr[rp + nd] - rs;
    }
    __syncthreads();
    int es = bptr[r * (NB + 1) + b], ee = bptr[r * (NB + 1) + b + 1];
    int sz = ee - es;
    size_t eb = (size_t)r * N_EDGES;
    if (sz <= 8192) {
        for (int i = es + tid; i < ee; i += 256) {
            unsigned u = ebin[eb + i];
            int dl = (int)((u >> 17) & 1023u);
            int rk = atomicAdd(&cnt[dl], 1);
            stage[rloc[dl] + rk] = (int)(u & 0x1FFFFu);
        }
        __syncthreads();
        for (int i = tid; i < sz; i += 256) csrc[eb + rs + i] = stage[i];
    } else {
        for (int i = es + tid; i < ee; i += 256) {
            unsigned u = ebin[eb + i];
            int dl = (int)((u >> 17) & 1023u);
            int rk = atomicAdd(&cnt[dl], 1);
            csrc[eb + rs + rloc[dl] + rk] = (int)(u & 0x1FFFFu);
        }
    }
}

// ---------------- W prep: f32 [k][col] -> bf16 [col][k ^ ((col&7)<<3)] ----------------
__global__ void k_wprep(const float* __restrict__ Ws, short* __restrict__ Wt) {
    int i = blockIdx.x * blockDim.x + threadIdx.x;
    if (i < 6 * 16384) {
        int lr = i >> 14, rem = i & 16383, k = rem >> 7, col = rem & 127;
        Wt[lr * 16384 + col * 128 + (k ^ ((col & 7) << 3))] = f2bf(Ws[i]);
    }
}

// clf_W f32 [128 k][64 col] -> bf16 [col][k ^ ((col&7)<<3)]
__global__ void k_wprep2(const float* __restrict__ Wc, short* __restrict__ Wcb) {
    int i = blockIdx.x * blockDim.x + threadIdx.x;
    if (i < 8192) {
        int k = i >> 6, col = i & 63;
        Wcb[col * 128 + (k ^ ((col & 7) << 3))] = f2bf(Wc[i]);
    }
}

// ---------------- f32 -> bf16 bulk convert ----------------
__global__ void k_cvt(const float* __restrict__ in, short* __restrict__ out, int n) {
    int i = blockIdx.x * blockDim.x + threadIdx.x;
    int stride = gridDim.x * blockDim.x;
    for (int base = i * 8; base < n; base += stride * 8) {
        float4 x = *(const float4*)(in + base);
        float4 y = *(const float4*)(in + base + 4);
        short8v o;
        o[0] = f2bf(x.x); o[1] = f2bf(x.y); o[2] = f2bf(x.z); o[3] = f2bf(x.w);
        o[4] = f2bf(y.x); o[5] = f2bf(y.y); o[6] = f2bf(y.z); o[7] = f2bf(y.w);
        *(short8v*)(out + base) = o;
    }
}

// ---------------- MFMA GEMM: bf16 out + fused el/er ----------------
__global__ __launch_bounds__(256) void k_gemm(const short* __restrict__ Abf,
                                              const short* __restrict__ Wt,
                                              const float* __restrict__ al,
                                              const float* __restrict__ ar,
                                              short* __restrict__ outB,
                                              float4* __restrict__ elr, int nrows) {
    __shared__ __align__(16) short Wl[128 * 128];
    int tid = threadIdx.x;
    {
        const float4* srcv = (const float4*)Wt;
        float4* dstv = (float4*)Wl;
        #pragma unroll
        for (int i = 0; i < 8; i++) dstv[tid + i * 256] = srcv[tid + i * 256];
    }
    int lane = tid & 63, wid = tid >> 6;
    int q = lane >> 4, j = lane & 15;
    int rowbase = blockIdx.x * 128 + wid * 32;

    float alv[8], arv[8];
    #pragma unroll
    for (int cb = 0; cb < 8; cb++) { alv[cb] = al[cb * 16 + j]; arv[cb] = ar[cb * 16 + j]; }

    short8v a[2][4];
    #pragma unroll
    for (int rb = 0; rb < 2; rb++) {
        int row = rowbase + rb * 16 + j;
        const short* ap = Abf + (size_t)row * 128 + q * 8;
        bool ok = row < nrows;
        #pragma unroll
        for (int kk = 0; kk < 4; kk++)
            a[rb][kk] = ok ? *(const short8v*)(ap + kk * 32) : (short8v)0;
    }
    __syncthreads();

    f32x4 acc[2][8] = {};
    #pragma unroll
    for (int cb = 0; cb < 8; cb++) {
        int col = cb * 16 + j;
        const short* wp = Wl + col * 128;
        int sw = (col & 7) << 3;
        #pragma unroll
        for (int kk = 0; kk < 4; kk++) {
            short8v b = *(const short8v*)(wp + ((kk * 32 + q * 8) ^ sw));
            acc[0][cb] = __builtin_amdgcn_mfma_f32_16x16x32_bf16(a[0][kk], b, acc[0][cb], 0, 0, 0);
            acc[1][cb] = __builtin_amdgcn_mfma_f32_16x16x32_bf16(a[1][kk], b, acc[1][cb], 0, 0, 0);
        }
    }

    #pragma unroll
    for (int rb = 0; rb < 2; rb++) {
        int row0 = rowbase + rb * 16 + q * 4;
        #pragma unroll
        for (int reg = 0; reg < 4; reg++) {
            int row = row0 + reg;
            if (row < nrows) {
                short* op = outB + (size_t)row * 128 + j;
                #pragma unroll
                for (int cb = 0; cb < 8; cb++) op[cb * 16] = f2bf(acc[rb][cb][reg]);
            }
        }
    }

    // fused el/er
    #pragma unroll
    for (int rb = 0; rb < 2; rb++) {
        float e0[4], e1[4], r0[4], r1[4];
        #pragma unroll
        for (int reg = 0; reg < 4; reg++) {
            float se0 = 0.f, se1 = 0.f, sr0 = 0.f, sr1 = 0.f;
            #pragma unroll
            for (int cb = 0; cb < 4; cb++) {
                se0 += acc[rb][cb][reg] * alv[cb];
                sr0 += acc[rb][cb][reg] * arv[cb];
                se1 += acc[rb][cb + 4][reg] * alv[cb + 4];
                sr1 += acc[rb][cb + 4][reg] * arv[cb + 4];
            }
            #pragma unroll
            for (int off = 1; off < 16; off <<= 1) {
                se0 += __shfl_xor(se0, off);
                se1 += __shfl_xor(se1, off);
                sr0 += __shfl_xor(sr0, off);
                sr1 += __shfl_xor(sr1, off);
            }
            e0[reg] = se0; e1[reg] = se1; r0[reg] = sr0; r1[reg] = sr1;
        }
        if (j < 4) {
            int row = rowbase + rb * 16 + q * 4 + j;
            if (row < nrows) {
                float4 v;
                v.x = j == 0 ? e0[0] : j == 1 ? e0[1] : j == 2 ? e0[2] : e0[3];
                v.y = j == 0 ? e1[0] : j == 1 ? e1[1] : j == 2 ? e1[2] : e1[3];
                v.z = j == 0 ? r0[0] : j == 1 ? r0[1] : j == 2 ? r0[2] : r0[3];
                v.w = j == 0 ? r1[0] : j == 1 ? r1[1] : j == 2 ? r1[2] : r1[3];
                elr[row] = v;
            }
        }
    }
}

// ---------------- fused softmax + gather-aggregate ----------------
// mode: 0 = store accb; 1 = accumulate accb; 2 = accumulate + relu -> bf16 hbf (skip accb write)
__global__ __launch_bounds__(256) void k_agg(const short* __restrict__ feat,
                                             const float4* __restrict__ elr,
                                             const int* __restrict__ rowptr,
                                             const int* __restrict__ csrc,
                                             const float* __restrict__ bias,
                                             float* __restrict__ acc,
                                             short* __restrict__ hb, int nrows, int mode) {
    int wid = threadIdx.x >> 6, lane = threadIdx.x & 63;
    int v = (blockIdx.x << 2) + wid;
    if (v >= nrows) return;
    int beg = rowptr[v], end = rowptr[v + 1], cnt = end - beg;
    float4 ev = elr[v];
    float m0 = -1e30f, m1 = -1e30f;
    if (cnt > 64) {
        for (int base = beg; base < end; base += 64) {
            int idx = base + lane;
            bool val = idx < end;
            int s = val ? csrc[idx] : 0;
            float4 es = elr[s];
            float e0 = es.x + ev.z; e0 = e0 >= 0.f ? e0 : NEG_SLOPE * e0;
            float e1 = es.y + ev.w; e1 = e1 >= 0.f ? e1 : NEG_SLOPE * e1;
            if (!val) { e0 = -1e30f; e1 = -1e30f; }
            #pragma unroll
            for (int off = 32; off; off >>= 1) {
                e0 = fmaxf(e0, __shfl_xor(e0, off));
                e1 = fmaxf(e1, __shfl_xor(e1, off));
            }
            m0 = fmaxf(m0, e0); m1 = fmaxf(m1, e1);
        }
    }
    float s0 = 0.f, s1 = 0.f, a0 = 0.f, a1 = 0.f;
    for (int base = beg; base < end; base += 64) {
        int idx = base + lane;
        bool val = idx < end;
        int sv = val ? csrc[idx] : 0;
        float4 es = elr[sv];
        float e0 = es.x + ev.z; e0 = e0 >= 0.f ? e0 : NEG_SLOPE * e0;
        float e1 = es.y + ev.w; e1 = e1 >= 0.f ? e1 : NEG_SLOPE * e1;
        if (cnt <= 64) {
            float t0 = val ? e0 : -1e30f, t1 = val ? e1 : -1e30f;
            #pragma unroll
            for (int off = 32; off; off >>= 1) {
                t0 = fmaxf(t0, __shfl_xor(t0, off));
                t1 = fmaxf(t1, __shfl_xor(t1, off));
            }
            m0 = t0; m1 = t1;
        }
        float p0 = val ? __expf(e0 - m0) : 0.f;
        float p1 = val ? __expf(e1 - m1) : 0.f;
        float q0 = p0, q1 = p1;
        #pragma unroll
        for (int off = 32; off; off >>= 1) {
            q0 += __shfl_xor(q0, off);
            q1 += __shfl_xor(q1, off);
        }
        s0 += q0; s1 += q1;
        int bc = min(64, end - base);
        for (int jj = 0; jj < bc; jj++) {
            int ss = __shfl(sv, jj);
            float pp0 = __shfl(p0, jj), pp1 = __shfl(p1, jj);
            float pp = lane < 32 ? pp0 : pp1;
            unsigned u = *(const unsigned*)(feat + (size_t)ss * 128 + (lane << 1));
            a0 += pp * bflo(u);
            a1 += pp * bfhi(u);
        }
    }
    float i0 = s0 > 0.f ? 1.0f / s0 : 0.f;
    float i1 = s1 > 0.f ? 1.0f / s1 : 0.f;
    float ii = lane < 32 ? i0 : i1;
    int c0 = lane << 1;
    float r0 = a0 * ii + bias[c0];
    float r1 = a1 * ii + bias[c0 + 1];
    float2* op = (float2*)(acc + (size_t)v * 128 + c0);
    if (mode == 0) {
        *op = make_float2(r0, r1);
    } else {
        float2 o = *op; r0 += o.x; r1 += o.y;
        if (mode == 1) {
            *op = make_float2(r0, r1);
        } else {  // mode 2: relu -> bf16 into hb, no accb write
            unsigned pk = ((unsigned)(unsigned short)f2bf(fmaxf(r0, 0.f))) |
                          (((unsigned)(unsigned short)f2bf(fmaxf(r1, 0.f))) << 16);
            *(unsigned*)(hb + (size_t)v * 128 + c0) = pk;
        }
    }
}

// ---------------- BN stats (fused relu, vectorized) ----------------
__global__ __launch_bounds__(256) void k_bnstat(const float4* __restrict__ h,
                                                float* __restrict__ sums, int nrows) {
    int tid = threadIdx.x;
    int c4 = tid & 31, rgrp = tid >> 5;
    float4 s = make_float4(0.f, 0.f, 0.f, 0.f), q = make_float4(0.f, 0.f, 0.f, 0.f);
    for (int row = blockIdx.x * 8 + rgrp; row < nrows; row += gridDim.x * 8) {
        float4 v = h[(size_t)row * 32 + c4];
        v.x = fmaxf(v.x, 0.f); v.y = fmaxf(v.y, 0.f);
        v.z = fmaxf(v.z, 0.f); v.w = fmaxf(v.w, 0.f);
        s.x += v.x; s.y += v.y; s.z += v.z; s.w += v.w;
        q.x += v.x * v.x; q.y += v.y * v.y; q.z += v.z * v.z; q.w += v.w * v.w;
    }
    __shared__ float ls[8][128], lq[8][128];
    *(float4*)&ls[rgrp][c4 * 4] = s;
    *(float4*)&lq[rgrp][c4 * 4] = q;
    __syncthreads();
    if (tid < 128) {
        float ts = 0.f, tq = 0.f;
        #pragma unroll
        for (int g = 0; g < 8; g++) { ts += ls[g][tid]; tq += lq[g][tid]; }
        atomicAdd(&sums[tid], ts);
        atomicAdd(&sums[128 + tid], tq);
    }
}

// ---------------- classifier: fused relu+BN-normalize -> bf16 MFMA GEMM [N,128]x[128,64] ----------------
__global__ __launch_bounds__(256) void k_clf(const float* __restrict__ h,
                                             const float* __restrict__ sums,
                                             const float* __restrict__ bn_w,
                                             const float* __restrict__ bn_b,
                                             const short* __restrict__ Wcb,
                                             const float* __restrict__ cbias,
                                             float* __restrict__ out, int nrows) {
    __shared__ __align__(16) short Wl[64 * 128];   // 16 KB, pre-swizzled [col][k^sw]
    __shared__ float2 bnp[128];
    int tid = threadIdx.x;
    {
        const float4* srcv = (const float4*)Wcb;
        float4* dstv = (float4*)Wl;
        #pragma unroll
        for (int i = 0; i < 4; i++) dstv[tid + i * 256] = srcv[tid + i * 256];
    }
    if (tid < 128) {
        float mu = sums[tid] / (float)nrows;
        float var = sums[128 + tid] / (float)nrows - mu * mu;
        float rs = rsqrtf(var + 1e-5f);
        float sc = bn_w[tid] * rs;
        bnp[tid] = make_float2(sc, bn_b[tid] - mu * sc);
    }
    __syncthreads();

    int lane = tid & 63, wid = tid >> 6;
    int q = lane >> 4, j = lane & 15;
    int rowbase = blockIdx.x * 128 + wid * 32;

    float cbv[4];
    #pragma unroll
    for (int cb = 0; cb < 4; cb++) cbv[cb] = cbias[cb * 16 + j];

    // A fragments: relu + BN-normalize accb rows, pack bf16
    short8v a[2][4];
    #pragma unroll
    for (int rb = 0; rb < 2; rb++) {
        int row = rowbase + rb * 16 + j;
        bool ok = row < nrows;
        const float* hp = h + (size_t)row * 128 + q * 8;
        #pragma unroll
        for (int kk = 0; kk < 4; kk++) {
            short8v av = (short8v)0;
            if (ok) {
                float4 x = *(const float4*)(hp + kk * 32);
                float4 y = *(const float4*)(hp + kk * 32 + 4);
                int k0 = kk * 32 + q * 8;
                float xs[8] = {x.x, x.y, x.z, x.w, y.x, y.y, y.z, y.w};
                #pragma unroll
                for (int i = 0; i < 8; i++) {
                    float2 bp = bnp[k0 + i];
                    av[i] = f2bf(fmaxf(xs[i], 0.f) * bp.x + bp.y);
                }
            }
            a[rb][kk] = av;
        }
    }

    f32x4 acc[2][4] = {};
    #pragma unroll
    for (int cb = 0; cb < 4; cb++) {
        int col = cb * 16 + j;
        const short* wp = Wl + col * 128;
        int sw = (col & 7) << 3;
        #pragma unroll
        for (int kk = 0; kk < 4; kk++) {
            short8v b = *(const short8v*)(wp + ((kk * 32 + q * 8) ^ sw));
            acc[0][cb] = __builtin_amdgcn_mfma_f32_16x16x32_bf16(a[0][kk], b, acc[0][cb], 0, 0, 0);
            acc[1][cb] = __builtin_amdgcn_mfma_f32_16x16x32_bf16(a[1][kk], b, acc[1][cb], 0, 0, 0);
        }
    }

    #pragma unroll
    for (int rb = 0; rb < 2; rb++) {
        int row0 = rowbase + rb * 16 + q * 4;
        #pragma unroll
        for (int reg = 0; reg < 4; reg++) {
            int row = row0 + reg;
            if (row < nrows) {
                float* op = out + (size_t)row * 64 + j;
                #pragma unroll
                for (int cb = 0; cb < 4; cb++) op[cb * 16] = acc[rb][cb][reg] + cbv[cb];
            }
        }
    }
}

// ---------------- launch ----------------

extern "C" void kernel_launch(void* const* d_in, const int* in_sizes, int n_in,
                              void* d_out, int out_size, void* d_ws, size_t ws_size,
                              hipStream_t stream) {
    (void)in_sizes; (void)n_in; (void)out_size; (void)ws_size;
    const float* feat_in = (const float*)d_in[0];
    const float* Ws      = (const float*)d_in[1];
    const float* als     = (const float*)d_in[2];
    const float* ars     = (const float*)d_in[3];
    const float* bs      = (const float*)d_in[4];
    const float* bn_w    = (const float*)d_in[5];
    const float* bn_b    = (const float*)d_in[6];
    const float* clf_W   = (const float*)d_in[7];
    const float* clf_b   = (const float*)d_in[8];
    const int*   src     = (const int*)d_in[9];
    const int*   dst     = (const int*)d_in[10];
    float* out = (float*)d_out;

    const int N = N_NODES, E = N_EDGES;
    char* p = (char*)d_ws;
    auto carve = [&](size_t bytes) { char* q = p; p += (bytes + 255) & ~255ULL; return q; };
    int*      bcnt   = (int*)carve((size_t)3 * NB * 4);
    int*      bptr   = (int*)carve((size_t)3 * (NB + 1) * 4);
    int*      bcur   = (int*)carve((size_t)3 * NB * 4);
    int*      rowptr = (int*)carve((size_t)3 * (N + 1) * 4);
    int*      csrc   = (int*)carve((size_t)3 * E * 4);
    unsigned* ebin   = (unsigned*)carve((size_t)3 * E * 4);
    float4*   elr    = (float4*)carve((size_t)N * 16);
    float*    bnsum  = (float*)carve(256 * 4);
    short*    Wtg    = (short*)carve((size_t)6 * 16384 * 2);
    short*    Wcb    = (short*)carve((size_t)8192 * 2);
    short*    hbf    = (short*)carve((size_t)N * 128 * 2);
    short*    featb  = (short*)carve((size_t)N * 128 * 2);
    float*    accb   = (float*)carve((size_t)N * 128 * 4);

    // weight prep + input conversion
    k_wprep<<<(6 * 16384 + 255) / 256, 256, 0, stream>>>(Ws, Wtg);
    k_wprep2<<<32, 256, 0, stream>>>(clf_W, Wcb);
    k_cvt<<<2048, 256, 0, stream>>>(feat_in, hbf, N * 128);

    // CSR build via binned sort
    hipMemsetAsync(bcnt, 0, (size_t)3 * NB * 4, stream);
    dim3 gchunk((E + 4095) / 4096, 3);
    k_bhist<<<gchunk, 256, 0, stream>>>(dst, bcnt);
    k_bscan<<<3, 64, 0, stream>>>(bcnt, bptr, bcur);
    k_bin<<<gchunk, 256, 0, stream>>>(src, dst, bcur, ebin);
    dim3 gbkt(NB, 3);
    k_nhist<<<gbkt, 256, 0, stream>>>(ebin, bptr, rowptr);
    k_scat2<<<gbkt, 256, 0, stream>>>(ebin, bptr, rowptr, csrc);

    for (int l = 0; l < 2; l++) {
        for (int r = 0; r < 3; r++) {
            int lr = l * 3 + r;
            int mode = (r == 0) ? 0 : ((r == 2 && l == 0) ? 2 : 1);
            k_gemm<<<(N + 127) / 128, 256, 0, stream>>>(hbf, Wtg + (size_t)lr * 16384,
                                                        als + lr * 128, ars + lr * 128,
                                                        featb, elr, N);
            k_agg<<<(N + 3) / 4, 256, 0, stream>>>(featb, elr, rowptr + r * (N + 1),
                                                   csrc + (size_t)r * E, bs + lr * 128,
                                                   accb, hbf, N, mode);
        }
    }

    hipMemsetAsync(bnsum, 0, 256 * 4, stream);
    k_bnstat<<<512, 256, 0, stream>>>((const float4*)accb, bnsum, N);
    k_clf<<<(N + 127) / 128, 256, 0, stream>>>(accb, bnsum, bn_w, bn_b, Wcb, clf_b, out, N);
}

// Round 7
// 461.867 us; speedup vs baseline: 4.7037x; 1.3050x over previous
//
#include <hip/hip_runtime.h>
#include <hip/hip_bf16.h>

#define N_NODES 100000
#define N_EDGES 500000
#define HID 128
#define NEG_SLOPE 0.2f
#define NB 98           // buckets of 1024 nodes: ceil(100000/1024)

typedef __attribute__((ext_vector_type(8))) short short8v;
typedef __attribute__((ext_vector_type(4))) short short4v;
typedef __attribute__((ext_vector_type(4))) float f32x4;

__device__ __forceinline__ short f2bf(float x) {
    union { float f; unsigned u; } v; v.f = x;
    unsigned r = v.u + 0x7fff + ((v.u >> 16) & 1);  // RNE
    return (short)(r >> 16);
}
__device__ __forceinline__ float bflo(unsigned u) {
    union { unsigned x; float f; } c; c.x = u << 16; return c.f;
}
__device__ __forceinline__ float bfhi(unsigned u) {
    union { unsigned x; float f; } c; c.x = u & 0xffff0000u; return c.f;
}
__device__ __forceinline__ float bfs(short s) {
    union { unsigned x; float f; } c; c.x = ((unsigned)(unsigned short)s) << 16; return c.f;
}

// ---------------- CSR build: binned two-level sort ----------------

__global__ __launch_bounds__(256) void k_bhist(const int* __restrict__ dst, int* __restrict__ bcnt) {
    int r = blockIdx.y, tid = threadIdx.x;
    int base = blockIdx.x * 4096;
    __shared__ int h[128];
    if (tid < 128) h[tid] = 0;
    __syncthreads();
    size_t eb = (size_t)r * N_EDGES;
    int lim = min(base + 4096, N_EDGES);
    for (int e = base + tid; e < lim; e += 256) atomicAdd(&h[dst[eb + e] >> 10], 1);
    __syncthreads();
    if (tid < NB && h[tid]) atomicAdd(&bcnt[r * NB + tid], h[tid]);
}

__global__ void k_bscan(const int* __restrict__ bcnt, int* __restrict__ bptr, int* __restrict__ bcur) {
    int r = blockIdx.x, lane = threadIdx.x;
    int carry = 0;
    for (int base = 0; base < NB; base += 64) {
        int i = base + lane;
        int c = (i < NB) ? bcnt[r * NB + i] : 0;
        int v = c;
        #pragma unroll
        for (int d = 1; d < 64; d <<= 1) { int t = __shfl_up(v, d); if (lane >= d) v += t; }
        int excl = carry + v - c;
        if (i < NB) { bptr[r * (NB + 1) + i] = excl; bcur[r * NB + i] = excl; }
        carry += __shfl(v, 63);
    }
    if (lane == 0) bptr[r * (NB + 1) + NB] = carry;
}

// bin edges into bucket regions of ebin packed as ((dst&1023)<<17 | src)
__global__ __launch_bounds__(256) void k_bin(const int* __restrict__ src, const int* __restrict__ dst,
                                             int* __restrict__ bcur, unsigned* __restrict__ ebin) {
    int r = blockIdx.y, tid = threadIdx.x;
    int base = blockIdx.x * 4096;
    __shared__ int cnt[128], incl[128], gb[128], wcur[128];
    __shared__ uint2 stage[4096];
    if (tid < 128) cnt[tid] = 0;
    __syncthreads();
    int myd[16], mys[16];
    size_t eb = (size_t)r * N_EDGES;
    #pragma unroll
    for (int i = 0; i < 16; i++) {
        int e = base + i * 256 + tid;
        if (e < N_EDGES) {
            int d = dst[eb + e];
            myd[i] = d; mys[i] = src[eb + e];
            atomicAdd(&cnt[d >> 10], 1);
        } else myd[i] = -1;
    }
    __syncthreads();
    if (tid < 128) incl[tid] = cnt[tid];
    __syncthreads();
    for (int d = 1; d < 128; d <<= 1) {
        int t = 0;
        if (tid < 128 && tid >= d) t = incl[tid - d];
        __syncthreads();
        if (tid < 128 && tid >= d) incl[tid] += t;
        __syncthreads();
    }
    if (tid < 128) {
        wcur[tid] = incl[tid] - cnt[tid];
        gb[tid] = (tid < NB && cnt[tid] > 0) ? atomicAdd(&bcur[r * NB + tid], cnt[tid]) : 0;
    }
    __syncthreads();
    #pragma unroll
    for (int i = 0; i < 16; i++) {
        if (myd[i] >= 0) {
            int bkt = myd[i] >> 10;
            int p = atomicAdd(&wcur[bkt], 1);
            stage[p] = make_uint2((unsigned)myd[i], (unsigned)mys[i]);
        }
    }
    __syncthreads();
    int tot = min(4096, N_EDGES - base);
    for (int i = tid; i < tot; i += 256) {
        uint2 u = stage[i];
        int bkt = (int)(u.x >> 10);
        int ex = incl[bkt] - cnt[bkt];
        ebin[eb + gb[bkt] + (i - ex)] = ((u.x & 1023u) << 17) | u.y;
    }
}

__global__ __launch_bounds__(256) void k_nhist(const unsigned* __restrict__ ebin,
                                               const int* __restrict__ bptr,
                                               int* __restrict__ rowptr) {
    int b = blockIdx.x, r = blockIdx.y, tid = threadIdx.x;
    __shared__ int cnt[1024];
    __shared__ int wsum[4];
    for (int i = tid; i < 1024; i += 256) cnt[i] = 0;
    __syncthreads();
    int es = bptr[r * (NB + 1) + b], ee = bptr[r * (NB + 1) + b + 1];
    size_t eb = (size_t)r * N_EDGES;
    for (int i = es + tid; i < ee; i += 256) atomicAdd(&cnt[(ebin[eb + i] >> 17) & 1023u], 1);
    __syncthreads();
    int b4 = tid * 4;
    int c0 = cnt[b4], c1 = cnt[b4 + 1], c2 = cnt[b4 + 2], c3 = cnt[b4 + 3];
    int ts = c0 + c1 + c2 + c3;
    int lane = tid & 63, wid = tid >> 6;
    int v = ts;
    #pragma unroll
    for (int d = 1; d < 64; d <<= 1) { int t = __shfl_up(v, d); if (lane >= d) v += t; }
    if (lane == 63) wsum[wid] = v;
    __syncthreads();
    int woff = 0;
    for (int w = 0; w < wid; w++) woff += wsum[w];
    int p = woff + v - ts;
    int node0 = b << 10;
    int rp = r * (N_NODES + 1);
    int nd;
    nd = node0 + b4;     if (nd < N_NODES) rowptr[rp + nd] = es + p; p += c0;
    nd = node0 + b4 + 1; if (nd < N_NODES) rowptr[rp + nd] = es + p; p += c1;
    nd = node0 + b4 + 2; if (nd < N_NODES) rowptr[rp + nd] = es + p; p += c2;
    nd = node0 + b4 + 3; if (nd < N_NODES) rowptr[rp + nd] = es + p;
    if (b == NB - 1 && tid == 0) rowptr[rp + N_NODES] = bptr[r * (NB + 1) + NB];
}

__global__ __launch_bounds__(256) void k_scat2(const unsigned* __restrict__ ebin,
                                               const int* __restrict__ bptr,
                                               const int* __restrict__ rowptr,
                                               int* __restrict__ csrc) {
    int b = blockIdx.x, r = blockIdx.y, tid = threadIdx.x;
    __shared__ int cnt[1024];
    __shared__ int rloc[1024];
    __shared__ int stage[8192];
    int node0 = b << 10;
    int rp = r * (N_NODES + 1);
    int rs = rowptr[rp + node0];
    for (int i = tid; i < 1024; i += 256) {
        cnt[i] = 0;
        int nd = node0 + i; if (nd > N_NODES) nd = N_NODES;
        rloc[i] = rowptr[rp + nd] - rs;
    }
    __syncthreads();
    int es = bptr[r * (NB + 1) + b], ee = bptr[r * (NB + 1) + b + 1];
    int sz = ee - es;
    size_t eb = (size_t)r * N_EDGES;
    if (sz <= 8192) {
        for (int i = es + tid; i < ee; i += 256) {
            unsigned u = ebin[eb + i];
            int dl = (int)((u >> 17) & 1023u);
            int rk = atomicAdd(&cnt[dl], 1);
            stage[rloc[dl] + rk] = (int)(u & 0x1FFFFu);
        }
        __syncthreads();
        for (int i = tid; i < sz; i += 256) csrc[eb + rs + i] = stage[i];
    } else {
        for (int i = es + tid; i < ee; i += 256) {
            unsigned u = ebin[eb + i];
            int dl = (int)((u >> 17) & 1023u);
            int rk = atomicAdd(&cnt[dl], 1);
            csrc[eb + rs + rloc[dl] + rk] = (int)(u & 0x1FFFFu);
        }
    }
}

// ---------------- W prep: f32 [k][col] -> bf16 [col][k ^ ((col&7)<<3)] ----------------
__global__ void k_wprep(const float* __restrict__ Ws, short* __restrict__ Wt) {
    int i = blockIdx.x * blockDim.x + threadIdx.x;
    if (i < 6 * 16384) {
        int lr = i >> 14, rem = i & 16383, k = rem >> 7, col = rem & 127;
        Wt[lr * 16384 + col * 128 + (k ^ ((col & 7) << 3))] = f2bf(Ws[i]);
    }
}

// clf_W f32 [128 k][64 col] -> bf16 [col][k ^ ((col&7)<<3)]
__global__ void k_wprep2(const float* __restrict__ Wc, short* __restrict__ Wcb) {
    int i = blockIdx.x * blockDim.x + threadIdx.x;
    if (i < 8192) {
        int k = i >> 6, col = i & 63;
        Wcb[col * 128 + (k ^ ((col & 7) << 3))] = f2bf(Wc[i]);
    }
}

// ---------------- f32 -> bf16 bulk convert ----------------
__global__ void k_cvt(const float* __restrict__ in, short* __restrict__ out, int n) {
    int i = blockIdx.x * blockDim.x + threadIdx.x;
    int stride = gridDim.x * blockDim.x;
    for (int base = i * 8; base < n; base += stride * 8) {
        float4 x = *(const float4*)(in + base);
        float4 y = *(const float4*)(in + base + 4);
        short8v o;
        o[0] = f2bf(x.x); o[1] = f2bf(x.y); o[2] = f2bf(x.z); o[3] = f2bf(x.w);
        o[4] = f2bf(y.x); o[5] = f2bf(y.y); o[6] = f2bf(y.z); o[7] = f2bf(y.w);
        *(short8v*)(out + base) = o;
    }
}

// ---------------- MFMA GEMM: bf16 out + fused el/er ----------------
__global__ __launch_bounds__(256) void k_gemm(const short* __restrict__ Abf,
                                              const short* __restrict__ Wt,
                                              const float* __restrict__ al,
                                              const float* __restrict__ ar,
                                              short* __restrict__ outB,
                                              float4* __restrict__ elr, int nrows) {
    __shared__ __align__(16) short Wl[128 * 128];
    int tid = threadIdx.x;
    {
        const float4* srcv = (const float4*)Wt;
        float4* dstv = (float4*)Wl;
        #pragma unroll
        for (int i = 0; i < 8; i++) dstv[tid + i * 256] = srcv[tid + i * 256];
    }
    int lane = tid & 63, wid = tid >> 6;
    int q = lane >> 4, j = lane & 15;
    int rowbase = blockIdx.x * 128 + wid * 32;

    float alv[8], arv[8];
    #pragma unroll
    for (int cb = 0; cb < 8; cb++) { alv[cb] = al[cb * 16 + j]; arv[cb] = ar[cb * 16 + j]; }

    short8v a[2][4];
    #pragma unroll
    for (int rb = 0; rb < 2; rb++) {
        int row = rowbase + rb * 16 + j;
        const short* ap = Abf + (size_t)row * 128 + q * 8;
        bool ok = row < nrows;
        #pragma unroll
        for (int kk = 0; kk < 4; kk++)
            a[rb][kk] = ok ? *(const short8v*)(ap + kk * 32) : (short8v)0;
    }
    __syncthreads();

    f32x4 acc[2][8] = {};
    #pragma unroll
    for (int cb = 0; cb < 8; cb++) {
        int col = cb * 16 + j;
        const short* wp = Wl + col * 128;
        int sw = (col & 7) << 3;
        #pragma unroll
        for (int kk = 0; kk < 4; kk++) {
            short8v b = *(const short8v*)(wp + ((kk * 32 + q * 8) ^ sw));
            acc[0][cb] = __builtin_amdgcn_mfma_f32_16x16x32_bf16(a[0][kk], b, acc[0][cb], 0, 0, 0);
            acc[1][cb] = __builtin_amdgcn_mfma_f32_16x16x32_bf16(a[1][kk], b, acc[1][cb], 0, 0, 0);
        }
    }

    #pragma unroll
    for (int rb = 0; rb < 2; rb++) {
        int row0 = rowbase + rb * 16 + q * 4;
        #pragma unroll
        for (int reg = 0; reg < 4; reg++) {
            int row = row0 + reg;
            if (row < nrows) {
                short* op = outB + (size_t)row * 128 + j;
                #pragma unroll
                for (int cb = 0; cb < 8; cb++) op[cb * 16] = f2bf(acc[rb][cb][reg]);
            }
        }
    }

    // fused el/er
    #pragma unroll
    for (int rb = 0; rb < 2; rb++) {
        float e0[4], e1[4], r0[4], r1[4];
        #pragma unroll
        for (int reg = 0; reg < 4; reg++) {
            float se0 = 0.f, se1 = 0.f, sr0 = 0.f, sr1 = 0.f;
            #pragma unroll
            for (int cb = 0; cb < 4; cb++) {
                se0 += acc[rb][cb][reg] * alv[cb];
                sr0 += acc[rb][cb][reg] * arv[cb];
                se1 += acc[rb][cb + 4][reg] * alv[cb + 4];
                sr1 += acc[rb][cb + 4][reg] * arv[cb + 4];
            }
            #pragma unroll
            for (int off = 1; off < 16; off <<= 1) {
                se0 += __shfl_xor(se0, off);
                se1 += __shfl_xor(se1, off);
                sr0 += __shfl_xor(sr0, off);
                sr1 += __shfl_xor(sr1, off);
            }
            e0[reg] = se0; e1[reg] = se1; r0[reg] = sr0; r1[reg] = sr1;
        }
        if (j < 4) {
            int row = rowbase + rb * 16 + q * 4 + j;
            if (row < nrows) {
                float4 v;
                v.x = j == 0 ? e0[0] : j == 1 ? e0[1] : j == 2 ? e0[2] : e0[3];
                v.y = j == 0 ? e1[0] : j == 1 ? e1[1] : j == 2 ? e1[2] : e1[3];
                v.z = j == 0 ? r0[0] : j == 1 ? r0[1] : j == 2 ? r0[2] : r0[3];
                v.w = j == 0 ? r1[0] : j == 1 ? r1[1] : j == 2 ? r1[2] : r1[3];
                elr[row] = v;
            }
        }
    }
}

// ---------------- merged 3-relation softmax + gather-aggregate (wave per dst node) ----------------
// no-max softmax (|e| <= ~12, exp safe); sum accumulated in broadcast loop; relu'd bf16 out.
__global__ __launch_bounds__(256) void k_agg3(const short* __restrict__ feat,   // [3][N*128]
                                              const float4* __restrict__ elr,   // [3][N]
                                              const int* __restrict__ rowptr,   // [3][N+1]
                                              const int* __restrict__ csrc,     // [3][E]
                                              const float* __restrict__ bias,   // [3][128]
                                              short* __restrict__ outB, int nrows) {
    int wid = threadIdx.x >> 6, lane = threadIdx.x & 63;
    int v = (blockIdx.x << 2) + wid;
    if (v >= nrows) return;
    int c0 = lane << 1;

    int beg[3], end[3];
    #pragma unroll
    for (int r = 0; r < 3; r++) {
        beg[r] = rowptr[r * (N_NODES + 1) + v];
        end[r] = rowptr[r * (N_NODES + 1) + v + 1];
    }
    float4 ev[3];
    #pragma unroll
    for (int r = 0; r < 3; r++) ev[r] = elr[(size_t)r * N_NODES + v];

    int sv[3]; float p0[3], p1[3]; int bc[3];
    #pragma unroll
    for (int r = 0; r < 3; r++) {
        int cnt = end[r] - beg[r];
        bc[r] = min(64, cnt);
        sv[r] = (lane < cnt) ? csrc[(size_t)r * N_EDGES + beg[r] + lane] : 0;
    }
    #pragma unroll
    for (int r = 0; r < 3; r++) {
        float4 es = elr[(size_t)r * N_NODES + sv[r]];
        float e0 = es.x + ev[r].z; e0 = e0 >= 0.f ? e0 : NEG_SLOPE * e0;
        float e1 = es.y + ev[r].w; e1 = e1 >= 0.f ? e1 : NEG_SLOPE * e1;
        bool val = lane < (end[r] - beg[r]);
        p0[r] = val ? __expf(e0) : 0.f;
        p1[r] = val ? __expf(e1) : 0.f;
    }

    float a0[3] = {0.f, 0.f, 0.f}, a1[3] = {0.f, 0.f, 0.f}, sp[3] = {0.f, 0.f, 0.f};

    auto body = [&](int jj) {
        #pragma unroll
        for (int r = 0; r < 3; r++) {
            if (jj < bc[r]) {   // wave-uniform
                int ss = __shfl(sv[r], jj);
                float q0 = __shfl(p0[r], jj), q1 = __shfl(p1[r], jj);
                float pp = lane < 32 ? q0 : q1;
                unsigned u = *(const unsigned*)(feat + (size_t)r * N_NODES * 128 + ((size_t)ss << 7) + c0);
                sp[r] += pp;
                a0[r] += pp * bflo(u);
                a1[r] += pp * bfhi(u);
            }
        }
    };
    int mb = max(bc[0], max(bc[1], bc[2]));
    int jj = 0;
    for (; jj + 2 <= mb; jj += 2) { body(jj); body(jj + 1); }
    if (jj < mb) body(jj);

    // rare tail: degree > 64
    #pragma unroll
    for (int r = 0; r < 3; r++) {
        for (int base = beg[r] + 64; base < end[r]; base += 64) {
            int idx = base + lane;
            bool val = idx < end[r];
            int sv2 = val ? csrc[(size_t)r * N_EDGES + idx] : 0;
            float4 es = elr[(size_t)r * N_NODES + sv2];
            float e0 = es.x + ev[r].z; e0 = e0 >= 0.f ? e0 : NEG_SLOPE * e0;
            float e1 = es.y + ev[r].w; e1 = e1 >= 0.f ? e1 : NEG_SLOPE * e1;
            float q0 = val ? __expf(e0) : 0.f;
            float q1 = val ? __expf(e1) : 0.f;
            int bc2 = min(64, end[r] - base);
            for (int k = 0; k < bc2; k++) {
                int ss = __shfl(sv2, k);
                float u0 = __shfl(q0, k), u1 = __shfl(q1, k);
                float pp = lane < 32 ? u0 : u1;
                unsigned u = *(const unsigned*)(feat + (size_t)r * N_NODES * 128 + ((size_t)ss << 7) + c0);
                sp[r] += pp;
                a0[r] += pp * bflo(u);
                a1[r] += pp * bfhi(u);
            }
        }
    }

    float t0 = bias[c0] + bias[128 + c0] + bias[256 + c0];
    float t1 = bias[c0 + 1] + bias[128 + c0 + 1] + bias[256 + c0 + 1];
    #pragma unroll
    for (int r = 0; r < 3; r++) {
        float inv = sp[r] > 0.f ? 1.0f / sp[r] : 0.f;
        t0 += a0[r] * inv;
        t1 += a1[r] * inv;
    }
    unsigned pk = ((unsigned)(unsigned short)f2bf(fmaxf(t0, 0.f))) |
                  (((unsigned)(unsigned short)f2bf(fmaxf(t1, 0.f))) << 16);
    *(unsigned*)(outB + (size_t)v * 128 + c0) = pk;
}

// ---------------- BN stats (bf16 relu'd input, vectorized) ----------------
__global__ __launch_bounds__(256) void k_bnstat(const short* __restrict__ h,
                                                float* __restrict__ sums, int nrows) {
    int tid = threadIdx.x;
    int cg = tid & 15, rgrp = tid >> 4;   // 16 col-groups of 8 ch; 16 rows in parallel
    float s[8] = {}, q[8] = {};
    for (int row = blockIdx.x * 16 + rgrp; row < nrows; row += gridDim.x * 16) {
        short8v u = *(const short8v*)(h + (size_t)row * 128 + cg * 8);
        #pragma unroll
        for (int i = 0; i < 8; i++) {
            float x = bfs(u[i]);
            s[i] += x; q[i] += x * x;
        }
    }
    __shared__ float ls[16][128];
    __shared__ float lq[16][128];
    #pragma unroll
    for (int i = 0; i < 8; i++) { ls[rgrp][cg * 8 + i] = s[i]; lq[rgrp][cg * 8 + i] = q[i]; }
    __syncthreads();
    int t = tid;
    if (t < 128) {
        float ts = 0.f, tq = 0.f;
        #pragma unroll
        for (int g = 0; g < 16; g++) { ts += ls[g][t]; tq += lq[g][t]; }
        atomicAdd(&sums[t], ts);
        atomicAdd(&sums[128 + t], tq);
    }
}

// ---------------- classifier: BN-normalize (input pre-relu'd bf16) -> MFMA GEMM [N,128]x[128,64] ----------------
__global__ __launch_bounds__(256) void k_clf(const short* __restrict__ h,
                                             const float* __restrict__ sums,
                                             const float* __restrict__ bn_w,
                                             const float* __restrict__ bn_b,
                                             const short* __restrict__ Wcb,
                                             const float* __restrict__ cbias,
                                             float* __restrict__ out, int nrows) {
    __shared__ __align__(16) short Wl[64 * 128];   // 16 KB, pre-swizzled [col][k^sw]
    __shared__ float2 bnp[128];
    int tid = threadIdx.x;
    {
        const float4* srcv = (const float4*)Wcb;
        float4* dstv = (float4*)Wl;
        #pragma unroll
        for (int i = 0; i < 4; i++) dstv[tid + i * 256] = srcv[tid + i * 256];
    }
    if (tid < 128) {
        float mu = sums[tid] / (float)nrows;
        float var = sums[128 + tid] / (float)nrows - mu * mu;
        float rs = rsqrtf(var + 1e-5f);
        float sc = bn_w[tid] * rs;
        bnp[tid] = make_float2(sc, bn_b[tid] - mu * sc);
    }
    __syncthreads();

    int lane = tid & 63, wid = tid >> 6;
    int q = lane >> 4, j = lane & 15;
    int rowbase = blockIdx.x * 128 + wid * 32;

    float cbv[4];
    #pragma unroll
    for (int cb = 0; cb < 4; cb++) cbv[cb] = cbias[cb * 16 + j];

    short8v a[2][4];
    #pragma unroll
    for (int rb = 0; rb < 2; rb++) {
        int row = rowbase + rb * 16 + j;
        bool ok = row < nrows;
        const short* hp = h + (size_t)row * 128 + q * 8;
        #pragma unroll
        for (int kk = 0; kk < 4; kk++) {
            short8v u = ok ? *(const short8v*)(hp + kk * 32) : (short8v)0;
            int k0 = kk * 32 + q * 8;
            short8v av;
            #pragma unroll
            for (int i = 0; i < 8; i++) {
                float2 bp = bnp[k0 + i];
                av[i] = f2bf(bfs(u[i]) * bp.x + bp.y);
            }
            a[rb][kk] = av;
        }
    }

    f32x4 acc[2][4] = {};
    #pragma unroll
    for (int cb = 0; cb < 4; cb++) {
        int col = cb * 16 + j;
        const short* wp = Wl + col * 128;
        int sw = (col & 7) << 3;
        #pragma unroll
        for (int kk = 0; kk < 4; kk++) {
            short8v b = *(const short8v*)(wp + ((kk * 32 + q * 8) ^ sw));
            acc[0][cb] = __builtin_amdgcn_mfma_f32_16x16x32_bf16(a[0][kk], b, acc[0][cb], 0, 0, 0);
            acc[1][cb] = __builtin_amdgcn_mfma_f32_16x16x32_bf16(a[1][kk], b, acc[1][cb], 0, 0, 0);
        }
    }

    #pragma unroll
    for (int rb = 0; rb < 2; rb++) {
        int row0 = rowbase + rb * 16 + q * 4;
        #pragma unroll
        for (int reg = 0; reg < 4; reg++) {
            int row = row0 + reg;
            if (row < nrows) {
                float* op = out + (size_t)row * 64 + j;
                #pragma unroll
                for (int cb = 0; cb < 4; cb++) op[cb * 16] = acc[rb][cb][reg] + cbv[cb];
            }
        }
    }
}

// ---------------- launch ----------------

extern "C" void kernel_launch(void* const* d_in, const int* in_sizes, int n_in,
                              void* d_out, int out_size, void* d_ws, size_t ws_size,
                              hipStream_t stream) {
    (void)in_sizes; (void)n_in; (void)out_size; (void)ws_size;
    const float* feat_in = (const float*)d_in[0];
    const float* Ws      = (const float*)d_in[1];
    const float* als     = (const float*)d_in[2];
    const float* ars     = (const float*)d_in[3];
    const float* bs      = (const float*)d_in[4];
    const float* bn_w    = (const float*)d_in[5];
    const float* bn_b    = (const float*)d_in[6];
    const float* clf_W   = (const float*)d_in[7];
    const float* clf_b   = (const float*)d_in[8];
    const int*   src     = (const int*)d_in[9];
    const int*   dst     = (const int*)d_in[10];
    float* out = (float*)d_out;

    const int N = N_NODES, E = N_EDGES;
    char* p = (char*)d_ws;
    auto carve = [&](size_t bytes) { char* q = p; p += (bytes + 255) & ~255ULL; return q; };
    int*      bcnt   = (int*)carve((size_t)3 * NB * 4);
    int*      bptr   = (int*)carve((size_t)3 * (NB + 1) * 4);
    int*      bcur   = (int*)carve((size_t)3 * NB * 4);
    int*      rowptr = (int*)carve((size_t)3 * (N + 1) * 4);
    int*      csrc   = (int*)carve((size_t)3 * E * 4);
    unsigned* ebin   = (unsigned*)carve((size_t)3 * E * 4);
    float4*   elr    = (float4*)carve((size_t)3 * N * 16);
    float*    bnsum  = (float*)carve(256 * 4);
    short*    Wtg    = (short*)carve((size_t)6 * 16384 * 2);
    short*    Wcb    = (short*)carve((size_t)8192 * 2);
    short*    hA     = (short*)carve((size_t)N * 128 * 2);
    short*    hB     = (short*)carve((size_t)N * 128 * 2);
    short*    featb  = (short*)carve((size_t)3 * N * 128 * 2);

    // weight prep + input conversion
    k_wprep<<<(6 * 16384 + 255) / 256, 256, 0, stream>>>(Ws, Wtg);
    k_wprep2<<<32, 256, 0, stream>>>(clf_W, Wcb);
    k_cvt<<<2048, 256, 0, stream>>>(feat_in, hA, N * 128);

    // CSR build via binned sort
    hipMemsetAsync(bcnt, 0, (size_t)3 * NB * 4, stream);
    dim3 gchunk((E + 4095) / 4096, 3);
    k_bhist<<<gchunk, 256, 0, stream>>>(dst, bcnt);
    k_bscan<<<3, 64, 0, stream>>>(bcnt, bptr, bcur);
    k_bin<<<gchunk, 256, 0, stream>>>(src, dst, bcur, ebin);
    dim3 gbkt(NB, 3);
    k_nhist<<<gbkt, 256, 0, stream>>>(ebin, bptr, rowptr);
    k_scat2<<<gbkt, 256, 0, stream>>>(ebin, bptr, rowptr, csrc);

    for (int l = 0; l < 2; l++) {
        const short* hin = (l == 0) ? hA : hB;
        short* hout = (l == 0) ? hB : hA;
        for (int r = 0; r < 3; r++) {
            int lr = l * 3 + r;
            k_gemm<<<(N + 127) / 128, 256, 0, stream>>>(hin, Wtg + (size_t)lr * 16384,
                                                        als + lr * 128, ars + lr * 128,
                                                        featb + (size_t)r * N * 128,
                                                        elr + (size_t)r * N, N);
        }
        k_agg3<<<(N + 3) / 4, 256, 0, stream>>>(featb, elr, rowptr, csrc,
                                                bs + (size_t)l * 384, hout, N);
    }

    // hA now holds layer-2 output (relu'd, bf16)
    hipMemsetAsync(bnsum, 0, 256 * 4, stream);
    k_bnstat<<<512, 256, 0, stream>>>(hA, bnsum, N);
    k_clf<<<(N + 127) / 128, 256, 0, stream>>>(hA, bnsum, bn_w, bn_b, Wcb, clf_b, out, N);
}